// Round 19
// baseline (210.514 us; speedup 1.0000x reference)
//
#include <hip/hip_runtime.h>
#include <math.h>

__device__ __forceinline__ float silu(float x) { return x / (1.0f + __expf(-x)); }

typedef __attribute__((ext_vector_type(8))) short short8v;  // 8 bf16 (4 VGPRs)
typedef __attribute__((ext_vector_type(4))) float f32x4;

__device__ __forceinline__ unsigned short f2bf(float x) {
  unsigned int u = __float_as_uint(x);
  return (unsigned short)((u + 0x8000u) >> 16);
}

// ---------------- Kernel 1: node precompute via bf16 MFMA (R16 proven) -----
__global__ __launch_bounds__(256) void node_pre_kernel(
    const float* __restrict__ nf, const float* __restrict__ na,
    const float* __restrict__ w0, const float* __restrict__ w1,
    const float* __restrict__ scw0, const float* __restrict__ scw1,
    float* __restrict__ y, float* __restrict__ sc, int N)
{
  __shared__ float nfL[32][132];
  __shared__ __align__(16) char aB[4096];
  __shared__ __align__(16) char wB[32768];
  const int t = threadIdx.x;
  const int n0 = blockIdx.x * 32;
  const int wv = t >> 6, l = t & 63;
  const int lrow = l & 15, lkg = l >> 4;
  const int ann = t >> 3, ac = t & 7;
  const float inv_sqrt32 = 0.17677669529663687f;
  const float sc_norm    = 0.08838834764831843f;  // 1/sqrt(32*4)

  for (int x4 = t; x4 < 1024; x4 += 256) {
    const int nn = x4 >> 5, c4 = x4 & 31;
    const int n = n0 + nn;
    float4 v = make_float4(0.f, 0.f, 0.f, 0.f);
    if (n < N) v = *(const float4*)(nf + (size_t)n * 128 + c4 * 4);
    *(float4*)&nfL[nn][c4 * 4] = v;
  }
  if (t < 128) {
    const int nn = t >> 2, c = t & 3;
    const int n = n0 + nn;
    nfL[nn][128 + c] = (n < N) ? na[(size_t)n * 4 + c] : 0.f;
  }
  for (int x = t; x < 1024; x += 256) {
    const int u = x >> 5, w = x & 31;
    *(unsigned short*)(wB + 0 + w * 128 + (((u >> 3) ^ (w & 7)) * 16) + (u & 7) * 2) = f2bf(w0[x]);
  }
  for (int x = t; x < 1024; x += 256) {
    const int u = x >> 5, w = x & 31;
    *(unsigned short*)(wB + 4096 + w * 128 + (((u >> 3) ^ (w & 7)) * 16) + (u & 7) * 2) = f2bf(w1[x]);
  }
  for (int x = t; x < 8192; x += 256) {
    const int k = x >> 6, c = x & 63;
    const int half = k >> 6, kk = k & 63;
    *(unsigned short*)(wB + 8192 + half * 8192 + c * 128 + (((kk >> 3) ^ (c & 7)) * 16) + (kk & 7) * 2) = f2bf(scw0[x]);
  }
  for (int x = t; x < 4096; x += 256) {
    const int k = x >> 5, c = x & 31;
    const int half = k >> 6, kk = k & 63;
    *(unsigned short*)(wB + 24576 + half * 4096 + c * 128 + (((kk >> 3) ^ (c & 7)) * 16) + (kk & 7) * 2) = f2bf(scw1[x]);
  }
  __syncthreads();

  if (ac < 4) {
    short8v hv;
#pragma unroll
    for (int j = 0; j < 8; ++j) hv[j] = (short)f2bf(nfL[ann][ac * 8 + j]);
    *(short8v*)(aB + ann * 128 + ((ac ^ (ann & 7)) * 16)) = hv;
  }
  __syncthreads();
  {
    const int mt = wv >> 1, nt = wv & 1;
    const int ar = mt * 16 + lrow, br = nt * 16 + lrow;
    const short8v A = *(const short8v*)(aB + ar * 128 + ((lkg ^ (ar & 7)) * 16));
    const short8v B = *(const short8v*)(wB + 0 + br * 128 + ((lkg ^ (br & 7)) * 16));
    f32x4 acc = (f32x4){0.f, 0.f, 0.f, 0.f};
    acc = __builtin_amdgcn_mfma_f32_16x16x32_bf16(A, B, acc, 0, 0, 0);
#pragma unroll
    for (int r = 0; r < 4; ++r) {
      const int nn = mt * 16 + lkg * 4 + r;
      const int n = n0 + nn;
      if (n < N) y[(size_t)n * 128 + nt * 16 + lrow] = acc[r] * inv_sqrt32;
    }
  }
  __syncthreads();

  for (int i = 0; i < 3; ++i) {
    if (ac < 4) {
      short8v hv;
#pragma unroll
      for (int j = 0; j < 8; ++j)
        hv[j] = (short)f2bf(nfL[ann][32 + (ac * 8 + j) * 3 + i]);
      *(short8v*)(aB + ann * 128 + ((ac ^ (ann & 7)) * 16)) = hv;
    }
    __syncthreads();
    {
      const int mt = wv >> 1, nt = wv & 1;
      const int ar = mt * 16 + lrow, br = nt * 16 + lrow;
      const short8v A = *(const short8v*)(aB + ar * 128 + ((lkg ^ (ar & 7)) * 16));
      const short8v B = *(const short8v*)(wB + 4096 + br * 128 + ((lkg ^ (br & 7)) * 16));
      f32x4 acc = (f32x4){0.f, 0.f, 0.f, 0.f};
      acc = __builtin_amdgcn_mfma_f32_16x16x32_bf16(A, B, acc, 0, 0, 0);
#pragma unroll
      for (int r = 0; r < 4; ++r) {
        const int nn = mt * 16 + lkg * 4 + r;
        const int n = n0 + nn;
        if (n < N) y[(size_t)n * 128 + 32 + (nt * 16 + lrow) * 3 + i] = acc[r] * inv_sqrt32;
      }
    }
    __syncthreads();
  }

  {
    f32x4 accS[2] = {(f32x4){0.f,0.f,0.f,0.f}, (f32x4){0.f,0.f,0.f,0.f}};
    const int mt = wv & 1, ntb = (wv >> 1) * 2;
#pragma unroll
    for (int half = 0; half < 2; ++half) {
      {
        short8v hv;
#pragma unroll
        for (int j = 0; j < 8; ++j) {
          const int k = half * 64 + ac * 8 + j;
          hv[j] = (short)f2bf(nfL[ann][k >> 2] * nfL[ann][128 + (k & 3)]);
        }
        *(short8v*)(aB + ann * 128 + ((ac ^ (ann & 7)) * 16)) = hv;
      }
      __syncthreads();
#pragma unroll
      for (int step = 0; step < 2; ++step) {
        const int ar = mt * 16 + lrow;
        const short8v A = *(const short8v*)(aB + ar * 128 + (((step * 4 + lkg) ^ (ar & 7)) * 16));
#pragma unroll
        for (int q = 0; q < 2; ++q) {
          const int br = (ntb + q) * 16 + lrow;
          const short8v B = *(const short8v*)(wB + 8192 + half * 8192 + br * 128 + (((step * 4 + lkg) ^ (br & 7)) * 16));
          accS[q] = __builtin_amdgcn_mfma_f32_16x16x32_bf16(A, B, accS[q], 0, 0, 0);
        }
      }
      __syncthreads();
    }
#pragma unroll
    for (int q = 0; q < 2; ++q) {
#pragma unroll
      for (int r = 0; r < 4; ++r) {
        const int nn = mt * 16 + lkg * 4 + r;
        const int n = n0 + nn;
        if (n < N) sc[(size_t)n * 160 + (ntb + q) * 16 + lrow] = accS[q][r] * sc_norm;
      }
    }
  }

  for (int i = 0; i < 3; ++i) {
    f32x4 acc = (f32x4){0.f, 0.f, 0.f, 0.f};
    const int mt = wv >> 1, nt = wv & 1;
#pragma unroll
    for (int half = 0; half < 2; ++half) {
      {
        short8v hv;
#pragma unroll
        for (int j = 0; j < 8; ++j) {
          const int k = half * 64 + ac * 8 + j;
          hv[j] = (short)f2bf(nfL[ann][32 + (k >> 2) * 3 + i] * nfL[ann][128 + (k & 3)]);
        }
        *(short8v*)(aB + ann * 128 + ((ac ^ (ann & 7)) * 16)) = hv;
      }
      __syncthreads();
#pragma unroll
      for (int step = 0; step < 2; ++step) {
        const int ar = mt * 16 + lrow;
        const short8v A = *(const short8v*)(aB + ar * 128 + (((step * 4 + lkg) ^ (ar & 7)) * 16));
        const int br = nt * 16 + lrow;
        const short8v B = *(const short8v*)(wB + 24576 + half * 4096 + br * 128 + (((step * 4 + lkg) ^ (br & 7)) * 16));
        acc = __builtin_amdgcn_mfma_f32_16x16x32_bf16(A, B, acc, 0, 0, 0);
      }
      __syncthreads();
    }
#pragma unroll
    for (int r = 0; r < 4; ++r) {
      const int nn = mt * 16 + lkg * 4 + r;
      const int n = n0 + nn;
      if (n < N) sc[(size_t)n * 160 + 64 + (nt * 16 + lrow) * 3 + i] = acc[r] * sc_norm;
    }
  }
}

// ---------------- CSR build ----------------
__global__ __launch_bounds__(256) void hist_kernel(const int* __restrict__ eidx,
                                                   int* __restrict__ counts, int E)
{
  const int e = blockIdx.x * 256 + threadIdx.x;
  if (e < E) atomicAdd(&counts[eidx[E + e]], 1);
}

__global__ __launch_bounds__(1024) void scan_kernel(const int* __restrict__ counts,
                                                    int* __restrict__ offsets,
                                                    int* __restrict__ cursor, int N)
{
  __shared__ int part[1024];
  const int t = threadIdx.x;
  const int per = (N + 1023) / 1024;
  const int base = t * per;
  int s = 0;
  for (int k = 0; k < per; ++k) { int idx = base + k; if (idx < N) s += counts[idx]; }
  part[t] = s;
  __syncthreads();
  for (int off = 1; off < 1024; off <<= 1) {
    int v = part[t];
    if (t >= off) v += part[t - off];
    __syncthreads();
    part[t] = v;
    __syncthreads();
  }
  int run = (t == 0) ? 0 : part[t - 1];
  for (int k = 0; k < per; ++k) {
    int idx = base + k;
    if (idx < N) { offsets[idx] = run; cursor[idx] = run; run += counts[idx]; }
  }
  if (t == 1023) offsets[N] = run;
}

// Scatter also materializes slot-ordered src + eattr (kills gather indirection).
__global__ __launch_bounds__(256) void scatter_kernel(
    const int* __restrict__ eidx, const float* __restrict__ eattr,
    int* __restrict__ cursor, int* __restrict__ elist,
    int* __restrict__ srcS, float4* __restrict__ eaS, int E)
{
  const int e = blockIdx.x * 256 + threadIdx.x;
  if (e >= E) return;
  const int dst = eidx[E + e];
  const int slot = atomicAdd(&cursor[dst], 1);
  elist[slot] = e;
  srcS[slot] = eidx[e];
  eaS[slot] = *(const float4*)(eattr + (size_t)e * 4);
}

// ---------------- Kernel 2: FUSED edge MLP; layers 2+3 via MFMA; bf16 out --
// wbuf layout INTERLEAVED: [slot][u][4] = {w00,w01,w10,w11} per u (u<32).
__global__ __launch_bounds__(256) void edge_mlp_kernel(
    const float* __restrict__ eemb, const float* __restrict__ fw1,
    const float* __restrict__ fw2, const float* __restrict__ fw3,
    const int* __restrict__ elist, unsigned short* __restrict__ wbuf, int E)
{
  __shared__ __align__(16) float w1L[512];     // [k<64][r<8] transposed, f32
  __shared__ __align__(16) char reg1[16384];
  __shared__ __align__(16) char reg2[32768];
  const int t = threadIdx.x;
  const int base = blockIdx.x * 128;

  for (int x = t; x < 512; x += 256)  w1L[x] = fw1[(x & 7) * 64 + (x >> 3)];
  for (int x = t; x < 4096; x += 256) {
    const int k = x >> 6, o = x & 63;
    *(unsigned short*)(reg2 + o * 128 + (((k >> 3) ^ (o & 7)) * 16) + (k & 7) * 2) = f2bf(fw2[x]);
  }

  const int e = t & 127, kg = t >> 7;
  {
    const int slot0 = base + e;
    const int eid = (slot0 < E) ? elist[slot0] : 0;
    const float4 em0 = *(const float4*)(eemb + (size_t)eid * 8);
    const float4 em1 = *(const float4*)(eemb + (size_t)eid * 8 + 4);
    __syncthreads();

    const float inv_sqrt8 = 0.35355339059327373f;
#pragma unroll
    for (int c = 0; c < 4; ++c) {
      short8v hv;
#pragma unroll
      for (int j = 0; j < 8; ++j) {
        const int k = kg * 32 + c * 8 + j;
        const float4 wa = *(const float4*)(w1L + k * 8);
        const float4 wb = *(const float4*)(w1L + k * 8 + 4);
        const float a = em0.x * wa.x + em0.y * wa.y + em0.z * wa.z + em0.w * wa.w
                      + em1.x * wb.x + em1.y * wb.y + em1.z * wb.z + em1.w * wb.w;
        hv[j] = (short)f2bf(silu(a * inv_sqrt8));
      }
      const int cc = kg * 4 + c;
      *(short8v*)(reg1 + e * 128 + ((cc ^ (e & 7)) * 16)) = hv;
    }
  }
  __syncthreads();

  const int wv = t >> 6, l = t & 63;
  const int lrow = l & 15, lkg = l >> 4;

  {
    f32x4 accB[2][4];
#pragma unroll
    for (int mt = 0; mt < 2; ++mt)
#pragma unroll
      for (int nt = 0; nt < 4; ++nt)
        accB[mt][nt] = (f32x4){0.f, 0.f, 0.f, 0.f};

#pragma unroll
    for (int step = 0; step < 2; ++step) {
#pragma unroll
      for (int mt = 0; mt < 2; ++mt) {
        const int ea = wv * 32 + mt * 16 + lrow;
        const short8v A = *(const short8v*)(reg1 + ea * 128 + (((step * 4 + lkg) ^ (ea & 7)) * 16));
#pragma unroll
        for (int nt = 0; nt < 4; ++nt) {
          const int o = nt * 16 + lrow;
          const short8v B = *(const short8v*)(reg2 + o * 128 + (((step * 4 + lkg) ^ (o & 7)) * 16));
          accB[mt][nt] = __builtin_amdgcn_mfma_f32_16x16x32_bf16(A, B, accB[mt][nt], 0, 0, 0);
        }
      }
    }
    __syncthreads();

#pragma unroll
    for (int mt = 0; mt < 2; ++mt) {
#pragma unroll
      for (int r = 0; r < 4; ++r) {
        const int eo = wv * 32 + mt * 16 + lkg * 4 + r;
#pragma unroll
        for (int nt = 0; nt < 4; ++nt) {
          const int o = nt * 16 + lrow;
          const float val = silu(accB[mt][nt][r] * 0.125f);
          *(unsigned short*)(reg1 + eo * 128 + (((o >> 3) ^ (eo & 7)) * 16) + (o & 7) * 2) = f2bf(val);
        }
      }
    }
  }
  for (int x = t; x < 8192; x += 256) {
    const int k = x >> 7, c = x & 127;
    *(unsigned short*)(reg2 + c * 128 + (((k >> 3) ^ (c & 7)) * 16) + (k & 7) * 2) = f2bf(fw3[x]);
  }
  __syncthreads();

  {
    f32x4 accd[2][8];
#pragma unroll
    for (int mt = 0; mt < 2; ++mt)
#pragma unroll
      for (int nt = 0; nt < 8; ++nt)
        accd[mt][nt] = (f32x4){0.f, 0.f, 0.f, 0.f};

#pragma unroll
    for (int step = 0; step < 2; ++step) {
      const int ea0 = wv * 32 + lrow;
      const int ea1 = wv * 32 + 16 + lrow;
      const short8v A0 = *(const short8v*)(reg1 + ea0 * 128 + (((step * 4 + lkg) ^ (ea0 & 7)) * 16));
      const short8v A1 = *(const short8v*)(reg1 + ea1 * 128 + (((step * 4 + lkg) ^ (ea1 & 7)) * 16));
#pragma unroll
      for (int nt = 0; nt < 8; ++nt) {
        const int n = nt * 16 + lrow;
        const short8v B = *(const short8v*)(reg2 + n * 128 + (((step * 4 + lkg) ^ (n & 7)) * 16));
        accd[0][nt] = __builtin_amdgcn_mfma_f32_16x16x32_bf16(A0, B, accd[0][nt], 0, 0, 0);
        accd[1][nt] = __builtin_amdgcn_mfma_f32_16x16x32_bf16(A1, B, accd[1][nt], 0, 0, 0);
      }
    }
    // Interleaved store: col = nt*16+lrow -> index (col&31)*4 + (col>>5)
#pragma unroll
    for (int mt = 0; mt < 2; ++mt) {
#pragma unroll
      for (int r = 0; r < 4; ++r) {
        const int eo = wv * 32 + mt * 16 + lkg * 4 + r;
        const int slot = base + eo;
        if (slot < E) {
          unsigned short* wrow = wbuf + (size_t)slot * 128;
#pragma unroll
          for (int nt = 0; nt < 8; ++nt) {
            const int uu = (nt & 1) * 16 + lrow;
            const int comp = nt >> 1;
            wrow[uu * 4 + comp] = f2bf(accd[mt][nt][r] * 0.125f);
          }
        }
      }
    }
  }
}

// ---------------- Kernel 3: wave-per-node gather, 1-load w, pipelined ------
__global__ __launch_bounds__(256) void gather_out_kernel(
    const float* __restrict__ nf, const unsigned short* __restrict__ wbuf,
    const float* __restrict__ y, const float* __restrict__ sc,
    const float* __restrict__ l2w0, const float* __restrict__ l2w1,
    const int* __restrict__ offsets, const int* __restrict__ srcS,
    const float4* __restrict__ eaS,
    const int* __restrict__ avgp, float* __restrict__ out, int N, int E)
{
  __shared__ float mW[4][264];    // per-wave m[256] (+pad)
  __shared__ float soW[4][160];   // per-wave so0[64] + so1[96]
  const int t = threadIdx.x;
  const int wv = t >> 6, l = t & 63;
  const int n = blockIdx.x * 4 + wv;
  const bool valid = (n < N);
  const int u = l & 31, half = l >> 5;

  const int beg = valid ? offsets[n] : 0;
  const int end = valid ? offsets[n + 1] : 0;

  float s0 = 0.f, s1 = 0.f;
  float v0x = 0.f, v0y = 0.f, v0z = 0.f;
  float v1x = 0.f, v1y = 0.f, v1z = 0.f;

  // 1-ahead pipeline on ALL streams (srcS, eaS, wbuf)
  int s = beg + half;
  int srcC = 0; float4 eaC = make_float4(0.f, 0.f, 0.f, 0.f);
  uint2 wrC = make_uint2(0u, 0u);
  if (s < end) {
    srcC = srcS[s]; eaC = eaS[s];
    wrC = *(const uint2*)(wbuf + (size_t)s * 128 + u * 4);
  }
  for (; s < end; ) {
    const int s2 = s + 2;
    int srcN = 0; float4 eaN = make_float4(0.f, 0.f, 0.f, 0.f);
    uint2 wrN = make_uint2(0u, 0u);
    if (s2 < end) {
      srcN = srcS[s2]; eaN = eaS[s2];
      wrN = *(const uint2*)(wbuf + (size_t)s2 * 128 + u * 4);
    }
    const float* yr = y + (size_t)srcC * 128;
    const float w00 = __uint_as_float(wrC.x << 16);
    const float w01 = __uint_as_float(wrC.x & 0xffff0000u);
    const float w10 = __uint_as_float(wrC.y << 16);
    const float w11 = __uint_as_float(wrC.y & 0xffff0000u);
    const float g0  = yr[u];
    const float g1x = yr[32 + 3 * u], g1y = yr[33 + 3 * u], g1z = yr[34 + 3 * u];
    s0 += w00 * g0 * eaC.x;
    const float t01 = w01 * g0;
    v0x += t01 * eaC.y; v0y += t01 * eaC.z; v0z += t01 * eaC.w;
    const float wg = w10 * eaC.x;
    v1x += wg * g1x; v1y += wg * g1y; v1z += wg * g1z;
    s1 += w11 * (g1x * eaC.y + g1y * eaC.z + g1z * eaC.w);
    s = s2; srcC = srcN; eaC = eaN; wrC = wrN;
  }
  s0 += __shfl_xor(s0, 32);  s1 += __shfl_xor(s1, 32);
  v0x += __shfl_xor(v0x, 32); v0y += __shfl_xor(v0y, 32); v0z += __shfl_xor(v0z, 32);
  v1x += __shfl_xor(v1x, 32); v1y += __shfl_xor(v1y, 32); v1z += __shfl_xor(v1z, 32);
  if (half == 0) {
    mW[wv][u]          = s0;
    mW[wv][32 + u]     = s1 * 0.5773502691896258f;
    mW[wv][64 + 3 * u] = v0x; mW[wv][65 + 3 * u] = v0y; mW[wv][66 + 3 * u] = v0z;
    mW[wv][160 + 3 * u] = v1x; mW[wv][161 + 3 * u] = v1y; mW[wv][162 + 3 * u] = v1z;
  }
  __syncthreads();

  const float scl = 0.125f * rsqrtf((float)(*avgp));
  const float* m = mW[wv];
  if (valid) {
    {
      float acc = 0.f;
      for (int uu = 0; uu < 64; ++uu) acc += m[uu] * l2w0[uu * 64 + l];
      soW[wv][l] = acc * scl + sc[(size_t)n * 160 + l];
    }
    {
      const int w = l / 3, i = l - 3 * w;
      float acc = 0.f;
      for (int uu = 0; uu < 64; ++uu) acc += m[64 + uu * 3 + i] * l2w1[uu * 32 + w];
      soW[wv][64 + l] = acc * scl + sc[(size_t)n * 160 + 64 + l];
    }
    if (l < 32) {
      const int q = 64 + l, w = q / 3, i = q - 3 * w;
      float acc = 0.f;
      for (int uu = 0; uu < 64; ++uu) acc += m[64 + uu * 3 + i] * l2w1[uu * 32 + w];
      soW[wv][64 + q] = acc * scl + sc[(size_t)n * 160 + 64 + q];
    }
  }
  __syncthreads();

  if (valid) {
#pragma unroll
    for (int p = 0; p < 2; ++p) {
      const int c = p * 64 + l;
      float val;
      if (c < 32) {
        val = silu(soW[wv][c]);
      } else {
        const int q = c - 32, w = q / 3, i = q - 3 * w;
        val = silu(soW[wv][32 + w]) * soW[wv][64 + w * 3 + i];
      }
      out[(size_t)n * 128 + c] = nf[(size_t)n * 128 + c] + val;
    }
  }
}

extern "C" void kernel_launch(void* const* d_in, const int* in_sizes, int n_in,
                              void* d_out, int out_size, void* d_ws, size_t ws_size,
                              hipStream_t stream)
{
  const float* nf    = (const float*)d_in[0];
  const float* na    = (const float*)d_in[1];
  const float* eattr = (const float*)d_in[2];
  const float* eemb  = (const float*)d_in[3];
  const float* l1w0  = (const float*)d_in[4];
  const float* l1w1  = (const float*)d_in[5];
  const float* fw1   = (const float*)d_in[6];
  const float* fw2   = (const float*)d_in[7];
  const float* fw3   = (const float*)d_in[8];
  const float* l2w0  = (const float*)d_in[9];
  const float* l2w1  = (const float*)d_in[10];
  const float* scw0  = (const float*)d_in[11];
  const float* scw1  = (const float*)d_in[12];
  const int*   eidx  = (const int*)d_in[13];
  const int*   avgp  = (const int*)d_in[14];

  const int N = in_sizes[0] / 128;
  const int E = in_sizes[2] / 4;

  // Same footprint as R3-R18: wbuf region (E*128 floats) holds bf16 wbuf
  // (first E*64 floats) + slot-ordered srcS (E ints) + eaS (E float4).
  float* y       = (float*)d_ws;                    // N*128
  float* sc      = y + (size_t)N * 128;             // N*160
  float* wbuff   = sc + (size_t)N * 160;            // E*128 floats reserved
  unsigned short* wbuf = (unsigned short*)wbuff;    // E*128 bf16 (= E*64 floats)
  int*    srcS   = (int*)(wbuff + (size_t)E * 64);  // E ints
  float4* eaS    = (float4*)(wbuff + (size_t)E * 64 + E);  // E float4 (16B-aligned)
  int*   counts  = (int*)(wbuff + (size_t)E * 128); // N
  int*   offsets = counts + N;                      // N+1
  int*   cursor  = offsets + N + 1;                 // N
  int*   elist   = cursor + N;                      // E (slot -> eid)

  hipMemsetAsync(counts, 0, (size_t)N * sizeof(int), stream);
  node_pre_kernel<<<(N + 31) / 32, 256, 0, stream>>>(nf, na, l1w0, l1w1, scw0, scw1, y, sc, N);
  hist_kernel<<<(E + 255) / 256, 256, 0, stream>>>(eidx, counts, E);
  scan_kernel<<<1, 1024, 0, stream>>>(counts, offsets, cursor, N);
  scatter_kernel<<<(E + 255) / 256, 256, 0, stream>>>(eidx, eattr, cursor, elist, srcS, eaS, E);
  edge_mlp_kernel<<<(E + 127) / 128, 256, 0, stream>>>(eemb, fw1, fw2, fw3, elist, wbuf, E);
  gather_out_kernel<<<(N + 3) / 4, 256, 0, stream>>>(nf, wbuf, y, sc, l2w0, l2w1,
                                                     offsets, srcS, eaS, avgp,
                                                     (float*)d_out, N, E);
}

// Round 20
// 207.838 us; speedup vs baseline: 1.0129x; 1.0129x over previous
//
#include <hip/hip_runtime.h>
#include <math.h>

__device__ __forceinline__ float silu(float x) { return x / (1.0f + __expf(-x)); }

typedef __attribute__((ext_vector_type(8))) short short8v;  // 8 bf16 (4 VGPRs)
typedef __attribute__((ext_vector_type(4))) float f32x4;

__device__ __forceinline__ unsigned short f2bf(float x) {
  unsigned int u = __float_as_uint(x);
  return (unsigned short)((u + 0x8000u) >> 16);
}

// ---------------- Kernel 1: node precompute via bf16 MFMA (R16 proven) -----
__global__ __launch_bounds__(256) void node_pre_kernel(
    const float* __restrict__ nf, const float* __restrict__ na,
    const float* __restrict__ w0, const float* __restrict__ w1,
    const float* __restrict__ scw0, const float* __restrict__ scw1,
    float* __restrict__ y, float* __restrict__ sc, int N)
{
  __shared__ float nfL[32][132];
  __shared__ __align__(16) char aB[4096];
  __shared__ __align__(16) char wB[32768];
  const int t = threadIdx.x;
  const int n0 = blockIdx.x * 32;
  const int wv = t >> 6, l = t & 63;
  const int lrow = l & 15, lkg = l >> 4;
  const int ann = t >> 3, ac = t & 7;
  const float inv_sqrt32 = 0.17677669529663687f;
  const float sc_norm    = 0.08838834764831843f;  // 1/sqrt(32*4)

  for (int x4 = t; x4 < 1024; x4 += 256) {
    const int nn = x4 >> 5, c4 = x4 & 31;
    const int n = n0 + nn;
    float4 v = make_float4(0.f, 0.f, 0.f, 0.f);
    if (n < N) v = *(const float4*)(nf + (size_t)n * 128 + c4 * 4);
    *(float4*)&nfL[nn][c4 * 4] = v;
  }
  if (t < 128) {
    const int nn = t >> 2, c = t & 3;
    const int n = n0 + nn;
    nfL[nn][128 + c] = (n < N) ? na[(size_t)n * 4 + c] : 0.f;
  }
  for (int x = t; x < 1024; x += 256) {
    const int u = x >> 5, w = x & 31;
    *(unsigned short*)(wB + 0 + w * 128 + (((u >> 3) ^ (w & 7)) * 16) + (u & 7) * 2) = f2bf(w0[x]);
  }
  for (int x = t; x < 1024; x += 256) {
    const int u = x >> 5, w = x & 31;
    *(unsigned short*)(wB + 4096 + w * 128 + (((u >> 3) ^ (w & 7)) * 16) + (u & 7) * 2) = f2bf(w1[x]);
  }
  for (int x = t; x < 8192; x += 256) {
    const int k = x >> 6, c = x & 63;
    const int half = k >> 6, kk = k & 63;
    *(unsigned short*)(wB + 8192 + half * 8192 + c * 128 + (((kk >> 3) ^ (c & 7)) * 16) + (kk & 7) * 2) = f2bf(scw0[x]);
  }
  for (int x = t; x < 4096; x += 256) {
    const int k = x >> 5, c = x & 31;
    const int half = k >> 6, kk = k & 63;
    *(unsigned short*)(wB + 24576 + half * 4096 + c * 128 + (((kk >> 3) ^ (c & 7)) * 16) + (kk & 7) * 2) = f2bf(scw1[x]);
  }
  __syncthreads();

  if (ac < 4) {
    short8v hv;
#pragma unroll
    for (int j = 0; j < 8; ++j) hv[j] = (short)f2bf(nfL[ann][ac * 8 + j]);
    *(short8v*)(aB + ann * 128 + ((ac ^ (ann & 7)) * 16)) = hv;
  }
  __syncthreads();
  {
    const int mt = wv >> 1, nt = wv & 1;
    const int ar = mt * 16 + lrow, br = nt * 16 + lrow;
    const short8v A = *(const short8v*)(aB + ar * 128 + ((lkg ^ (ar & 7)) * 16));
    const short8v B = *(const short8v*)(wB + 0 + br * 128 + ((lkg ^ (br & 7)) * 16));
    f32x4 acc = (f32x4){0.f, 0.f, 0.f, 0.f};
    acc = __builtin_amdgcn_mfma_f32_16x16x32_bf16(A, B, acc, 0, 0, 0);
#pragma unroll
    for (int r = 0; r < 4; ++r) {
      const int nn = mt * 16 + lkg * 4 + r;
      const int n = n0 + nn;
      if (n < N) y[(size_t)n * 128 + nt * 16 + lrow] = acc[r] * inv_sqrt32;
    }
  }
  __syncthreads();

  for (int i = 0; i < 3; ++i) {
    if (ac < 4) {
      short8v hv;
#pragma unroll
      for (int j = 0; j < 8; ++j)
        hv[j] = (short)f2bf(nfL[ann][32 + (ac * 8 + j) * 3 + i]);
      *(short8v*)(aB + ann * 128 + ((ac ^ (ann & 7)) * 16)) = hv;
    }
    __syncthreads();
    {
      const int mt = wv >> 1, nt = wv & 1;
      const int ar = mt * 16 + lrow, br = nt * 16 + lrow;
      const short8v A = *(const short8v*)(aB + ar * 128 + ((lkg ^ (ar & 7)) * 16));
      const short8v B = *(const short8v*)(wB + 4096 + br * 128 + ((lkg ^ (br & 7)) * 16));
      f32x4 acc = (f32x4){0.f, 0.f, 0.f, 0.f};
      acc = __builtin_amdgcn_mfma_f32_16x16x32_bf16(A, B, acc, 0, 0, 0);
#pragma unroll
      for (int r = 0; r < 4; ++r) {
        const int nn = mt * 16 + lkg * 4 + r;
        const int n = n0 + nn;
        if (n < N) y[(size_t)n * 128 + 32 + (nt * 16 + lrow) * 3 + i] = acc[r] * inv_sqrt32;
      }
    }
    __syncthreads();
  }

  {
    f32x4 accS[2] = {(f32x4){0.f,0.f,0.f,0.f}, (f32x4){0.f,0.f,0.f,0.f}};
    const int mt = wv & 1, ntb = (wv >> 1) * 2;
#pragma unroll
    for (int half = 0; half < 2; ++half) {
      {
        short8v hv;
#pragma unroll
        for (int j = 0; j < 8; ++j) {
          const int k = half * 64 + ac * 8 + j;
          hv[j] = (short)f2bf(nfL[ann][k >> 2] * nfL[ann][128 + (k & 3)]);
        }
        *(short8v*)(aB + ann * 128 + ((ac ^ (ann & 7)) * 16)) = hv;
      }
      __syncthreads();
#pragma unroll
      for (int step = 0; step < 2; ++step) {
        const int ar = mt * 16 + lrow;
        const short8v A = *(const short8v*)(aB + ar * 128 + (((step * 4 + lkg) ^ (ar & 7)) * 16));
#pragma unroll
        for (int q = 0; q < 2; ++q) {
          const int br = (ntb + q) * 16 + lrow;
          const short8v B = *(const short8v*)(wB + 8192 + half * 8192 + br * 128 + (((step * 4 + lkg) ^ (br & 7)) * 16));
          accS[q] = __builtin_amdgcn_mfma_f32_16x16x32_bf16(A, B, accS[q], 0, 0, 0);
        }
      }
      __syncthreads();
    }
#pragma unroll
    for (int q = 0; q < 2; ++q) {
#pragma unroll
      for (int r = 0; r < 4; ++r) {
        const int nn = mt * 16 + lkg * 4 + r;
        const int n = n0 + nn;
        if (n < N) sc[(size_t)n * 160 + (ntb + q) * 16 + lrow] = accS[q][r] * sc_norm;
      }
    }
  }

  for (int i = 0; i < 3; ++i) {
    f32x4 acc = (f32x4){0.f, 0.f, 0.f, 0.f};
    const int mt = wv >> 1, nt = wv & 1;
#pragma unroll
    for (int half = 0; half < 2; ++half) {
      {
        short8v hv;
#pragma unroll
        for (int j = 0; j < 8; ++j) {
          const int k = half * 64 + ac * 8 + j;
          hv[j] = (short)f2bf(nfL[ann][32 + (k >> 2) * 3 + i] * nfL[ann][128 + (k & 3)]);
        }
        *(short8v*)(aB + ann * 128 + ((ac ^ (ann & 7)) * 16)) = hv;
      }
      __syncthreads();
#pragma unroll
      for (int step = 0; step < 2; ++step) {
        const int ar = mt * 16 + lrow;
        const short8v A = *(const short8v*)(aB + ar * 128 + (((step * 4 + lkg) ^ (ar & 7)) * 16));
        const int br = nt * 16 + lrow;
        const short8v B = *(const short8v*)(wB + 24576 + half * 4096 + br * 128 + (((step * 4 + lkg) ^ (br & 7)) * 16));
        acc = __builtin_amdgcn_mfma_f32_16x16x32_bf16(A, B, acc, 0, 0, 0);
      }
      __syncthreads();
    }
#pragma unroll
    for (int r = 0; r < 4; ++r) {
      const int nn = mt * 16 + lkg * 4 + r;
      const int n = n0 + nn;
      if (n < N) sc[(size_t)n * 160 + 64 + (nt * 16 + lrow) * 3 + i] = acc[r] * sc_norm;
    }
  }
}

// ---------------- CSR build ----------------
__global__ __launch_bounds__(256) void hist_kernel(const int* __restrict__ eidx,
                                                   int* __restrict__ counts, int E)
{
  const int e = blockIdx.x * 256 + threadIdx.x;
  if (e < E) atomicAdd(&counts[eidx[E + e]], 1);
}

__global__ __launch_bounds__(1024) void scan_kernel(const int* __restrict__ counts,
                                                    int* __restrict__ offsets,
                                                    int* __restrict__ cursor, int N)
{
  __shared__ int part[1024];
  const int t = threadIdx.x;
  const int per = (N + 1023) / 1024;
  const int base = t * per;
  int s = 0;
  for (int k = 0; k < per; ++k) { int idx = base + k; if (idx < N) s += counts[idx]; }
  part[t] = s;
  __syncthreads();
  for (int off = 1; off < 1024; off <<= 1) {
    int v = part[t];
    if (t >= off) v += part[t - off];
    __syncthreads();
    part[t] = v;
    __syncthreads();
  }
  int run = (t == 0) ? 0 : part[t - 1];
  for (int k = 0; k < per; ++k) {
    int idx = base + k;
    if (idx < N) { offsets[idx] = run; cursor[idx] = run; run += counts[idx]; }
  }
  if (t == 1023) offsets[N] = run;
}

// Scatter also materializes slot-ordered src + eattr (kills gather indirection).
__global__ __launch_bounds__(256) void scatter_kernel(
    const int* __restrict__ eidx, const float* __restrict__ eattr,
    int* __restrict__ cursor, int* __restrict__ elist,
    int* __restrict__ srcS, float4* __restrict__ eaS, int E)
{
  const int e = blockIdx.x * 256 + threadIdx.x;
  if (e >= E) return;
  const int dst = eidx[E + e];
  const int slot = atomicAdd(&cursor[dst], 1);
  elist[slot] = e;
  srcS[slot] = eidx[e];
  eaS[slot] = *(const float4*)(eattr + (size_t)e * 4);
}

// ---------------- Kernel 2: FUSED edge MLP; layers 2+3 via MFMA; bf16 out --
// wbuf layout INTERLEAVED: [slot][u][4] = {w00,w01,w10,w11} per u (u<32).
__global__ __launch_bounds__(256) void edge_mlp_kernel(
    const float* __restrict__ eemb, const float* __restrict__ fw1,
    const float* __restrict__ fw2, const float* __restrict__ fw3,
    const int* __restrict__ elist, unsigned short* __restrict__ wbuf, int E)
{
  __shared__ __align__(16) float w1L[512];     // [k<64][r<8] transposed, f32
  __shared__ __align__(16) char reg1[16384];
  __shared__ __align__(16) char reg2[32768];
  const int t = threadIdx.x;
  const int base = blockIdx.x * 128;

  for (int x = t; x < 512; x += 256)  w1L[x] = fw1[(x & 7) * 64 + (x >> 3)];
  for (int x = t; x < 4096; x += 256) {
    const int k = x >> 6, o = x & 63;
    *(unsigned short*)(reg2 + o * 128 + (((k >> 3) ^ (o & 7)) * 16) + (k & 7) * 2) = f2bf(fw2[x]);
  }

  const int e = t & 127, kg = t >> 7;
  {
    const int slot0 = base + e;
    const int eid = (slot0 < E) ? elist[slot0] : 0;
    const float4 em0 = *(const float4*)(eemb + (size_t)eid * 8);
    const float4 em1 = *(const float4*)(eemb + (size_t)eid * 8 + 4);
    __syncthreads();

    const float inv_sqrt8 = 0.35355339059327373f;
#pragma unroll
    for (int c = 0; c < 4; ++c) {
      short8v hv;
#pragma unroll
      for (int j = 0; j < 8; ++j) {
        const int k = kg * 32 + c * 8 + j;
        const float4 wa = *(const float4*)(w1L + k * 8);
        const float4 wb = *(const float4*)(w1L + k * 8 + 4);
        const float a = em0.x * wa.x + em0.y * wa.y + em0.z * wa.z + em0.w * wa.w
                      + em1.x * wb.x + em1.y * wb.y + em1.z * wb.z + em1.w * wb.w;
        hv[j] = (short)f2bf(silu(a * inv_sqrt8));
      }
      const int cc = kg * 4 + c;
      *(short8v*)(reg1 + e * 128 + ((cc ^ (e & 7)) * 16)) = hv;
    }
  }
  __syncthreads();

  const int wv = t >> 6, l = t & 63;
  const int lrow = l & 15, lkg = l >> 4;

  {
    f32x4 accB[2][4];
#pragma unroll
    for (int mt = 0; mt < 2; ++mt)
#pragma unroll
      for (int nt = 0; nt < 4; ++nt)
        accB[mt][nt] = (f32x4){0.f, 0.f, 0.f, 0.f};

#pragma unroll
    for (int step = 0; step < 2; ++step) {
#pragma unroll
      for (int mt = 0; mt < 2; ++mt) {
        const int ea = wv * 32 + mt * 16 + lrow;
        const short8v A = *(const short8v*)(reg1 + ea * 128 + (((step * 4 + lkg) ^ (ea & 7)) * 16));
#pragma unroll
        for (int nt = 0; nt < 4; ++nt) {
          const int o = nt * 16 + lrow;
          const short8v B = *(const short8v*)(reg2 + o * 128 + (((step * 4 + lkg) ^ (o & 7)) * 16));
          accB[mt][nt] = __builtin_amdgcn_mfma_f32_16x16x32_bf16(A, B, accB[mt][nt], 0, 0, 0);
        }
      }
    }
    __syncthreads();

#pragma unroll
    for (int mt = 0; mt < 2; ++mt) {
#pragma unroll
      for (int r = 0; r < 4; ++r) {
        const int eo = wv * 32 + mt * 16 + lkg * 4 + r;
#pragma unroll
        for (int nt = 0; nt < 4; ++nt) {
          const int o = nt * 16 + lrow;
          const float val = silu(accB[mt][nt][r] * 0.125f);
          *(unsigned short*)(reg1 + eo * 128 + (((o >> 3) ^ (eo & 7)) * 16) + (o & 7) * 2) = f2bf(val);
        }
      }
    }
  }
  for (int x = t; x < 8192; x += 256) {
    const int k = x >> 7, c = x & 127;
    *(unsigned short*)(reg2 + c * 128 + (((k >> 3) ^ (c & 7)) * 16) + (k & 7) * 2) = f2bf(fw3[x]);
  }
  __syncthreads();

  {
    f32x4 accd[2][8];
#pragma unroll
    for (int mt = 0; mt < 2; ++mt)
#pragma unroll
      for (int nt = 0; nt < 8; ++nt)
        accd[mt][nt] = (f32x4){0.f, 0.f, 0.f, 0.f};

#pragma unroll
    for (int step = 0; step < 2; ++step) {
      const int ea0 = wv * 32 + lrow;
      const int ea1 = wv * 32 + 16 + lrow;
      const short8v A0 = *(const short8v*)(reg1 + ea0 * 128 + (((step * 4 + lkg) ^ (ea0 & 7)) * 16));
      const short8v A1 = *(const short8v*)(reg1 + ea1 * 128 + (((step * 4 + lkg) ^ (ea1 & 7)) * 16));
#pragma unroll
      for (int nt = 0; nt < 8; ++nt) {
        const int n = nt * 16 + lrow;
        const short8v B = *(const short8v*)(reg2 + n * 128 + (((step * 4 + lkg) ^ (n & 7)) * 16));
        accd[0][nt] = __builtin_amdgcn_mfma_f32_16x16x32_bf16(A0, B, accd[0][nt], 0, 0, 0);
        accd[1][nt] = __builtin_amdgcn_mfma_f32_16x16x32_bf16(A1, B, accd[1][nt], 0, 0, 0);
      }
    }
    // Interleaved store: col = nt*16+lrow -> index (col&31)*4 + (col>>5)
#pragma unroll
    for (int mt = 0; mt < 2; ++mt) {
#pragma unroll
      for (int r = 0; r < 4; ++r) {
        const int eo = wv * 32 + mt * 16 + lkg * 4 + r;
        const int slot = base + eo;
        if (slot < E) {
          unsigned short* wrow = wbuf + (size_t)slot * 128;
#pragma unroll
          for (int nt = 0; nt < 8; ++nt) {
            const int uu = (nt & 1) * 16 + lrow;
            const int comp = nt >> 1;
            wrow[uu * 4 + comp] = f2bf(accd[mt][nt][r] * 0.125f);
          }
        }
      }
    }
  }
}

// ---------------- Kernel 3: wave-per-node gather, 4-slot chunked MLP -------
__global__ __launch_bounds__(256) void gather_out_kernel(
    const float* __restrict__ nf, const unsigned short* __restrict__ wbuf,
    const float* __restrict__ y, const float* __restrict__ sc,
    const float* __restrict__ l2w0, const float* __restrict__ l2w1,
    const int* __restrict__ offsets, const int* __restrict__ srcS,
    const float4* __restrict__ eaS,
    const int* __restrict__ avgp, float* __restrict__ out, int N, int E)
{
  __shared__ float mW[4][264];    // per-wave m[256] (+pad)
  __shared__ float soW[4][160];   // per-wave so0[64] + so1[96]
  const int t = threadIdx.x;
  const int wv = t >> 6, l = t & 63;
  const int n = blockIdx.x * 4 + wv;
  const bool valid = (n < N);
  const int u = l & 31, half = l >> 5;

  const int beg = valid ? offsets[n] : 0;
  const int end = valid ? offsets[n + 1] : 0;
  const int s0 = beg + half;
  const int cnt = (s0 < end) ? ((end - s0 + 1) >> 1) : 0;

  float a_s0 = 0.f, a_s1 = 0.f;
  float v0x = 0.f, v0y = 0.f, v0z = 0.f;
  float v1x = 0.f, v1y = 0.f, v1z = 0.f;

  int i = 0;
  // ---- chunked-by-4: 4 independent y gathers in flight per wave ----
  for (; i + 4 <= cnt; i += 4) {
    int csrc[4]; float4 cea[4]; uint2 cw[4];
#pragma unroll
    for (int q = 0; q < 4; ++q) {
      const int sq = s0 + 2 * (i + q);
      csrc[q] = srcS[sq];
      cea[q]  = eaS[sq];
      cw[q]   = *(const uint2*)(wbuf + (size_t)sq * 128 + u * 4);
    }
    float cg0[4], cgx[4], cgy[4], cgz[4];
#pragma unroll
    for (int q = 0; q < 4; ++q) {
      const float* yr = y + (size_t)csrc[q] * 128;
      cg0[q] = yr[u];
      cgx[q] = yr[32 + 3 * u]; cgy[q] = yr[33 + 3 * u]; cgz[q] = yr[34 + 3 * u];
    }
#pragma unroll
    for (int q = 0; q < 4; ++q) {
      const float w00 = __uint_as_float(cw[q].x << 16);
      const float w01 = __uint_as_float(cw[q].x & 0xffff0000u);
      const float w10 = __uint_as_float(cw[q].y << 16);
      const float w11 = __uint_as_float(cw[q].y & 0xffff0000u);
      a_s0 += w00 * cg0[q] * cea[q].x;
      const float t01 = w01 * cg0[q];
      v0x += t01 * cea[q].y; v0y += t01 * cea[q].z; v0z += t01 * cea[q].w;
      const float wg = w10 * cea[q].x;
      v1x += wg * cgx[q]; v1y += wg * cgy[q]; v1z += wg * cgz[q];
      a_s1 += w11 * (cgx[q] * cea[q].y + cgy[q] * cea[q].z + cgz[q] * cea[q].w);
    }
  }
  // ---- remainder ----
  for (; i < cnt; ++i) {
    const int sq = s0 + 2 * i;
    const int src = srcS[sq];
    const float4 ea = eaS[sq];
    const uint2 wr = *(const uint2*)(wbuf + (size_t)sq * 128 + u * 4);
    const float* yr = y + (size_t)src * 128;
    const float w00 = __uint_as_float(wr.x << 16);
    const float w01 = __uint_as_float(wr.x & 0xffff0000u);
    const float w10 = __uint_as_float(wr.y << 16);
    const float w11 = __uint_as_float(wr.y & 0xffff0000u);
    const float g0  = yr[u];
    const float g1x = yr[32 + 3 * u], g1y = yr[33 + 3 * u], g1z = yr[34 + 3 * u];
    a_s0 += w00 * g0 * ea.x;
    const float t01 = w01 * g0;
    v0x += t01 * ea.y; v0y += t01 * ea.z; v0z += t01 * ea.w;
    const float wg = w10 * ea.x;
    v1x += wg * g1x; v1y += wg * g1y; v1z += wg * g1z;
    a_s1 += w11 * (g1x * ea.y + g1y * ea.z + g1z * ea.w);
  }

  a_s0 += __shfl_xor(a_s0, 32);  a_s1 += __shfl_xor(a_s1, 32);
  v0x += __shfl_xor(v0x, 32); v0y += __shfl_xor(v0y, 32); v0z += __shfl_xor(v0z, 32);
  v1x += __shfl_xor(v1x, 32); v1y += __shfl_xor(v1y, 32); v1z += __shfl_xor(v1z, 32);
  if (half == 0) {
    mW[wv][u]          = a_s0;
    mW[wv][32 + u]     = a_s1 * 0.5773502691896258f;
    mW[wv][64 + 3 * u] = v0x; mW[wv][65 + 3 * u] = v0y; mW[wv][66 + 3 * u] = v0z;
    mW[wv][160 + 3 * u] = v1x; mW[wv][161 + 3 * u] = v1y; mW[wv][162 + 3 * u] = v1z;
  }
  __syncthreads();

  const float scl = 0.125f * rsqrtf((float)(*avgp));
  const float* m = mW[wv];
  if (valid) {
    {
      float acc = 0.f;
      for (int uu = 0; uu < 64; ++uu) acc += m[uu] * l2w0[uu * 64 + l];
      soW[wv][l] = acc * scl + sc[(size_t)n * 160 + l];
    }
    {
      const int w = l / 3, i2 = l - 3 * w;
      float acc = 0.f;
      for (int uu = 0; uu < 64; ++uu) acc += m[64 + uu * 3 + i2] * l2w1[uu * 32 + w];
      soW[wv][64 + l] = acc * scl + sc[(size_t)n * 160 + 64 + l];
    }
    if (l < 32) {
      const int q = 64 + l, w = q / 3, i2 = q - 3 * w;
      float acc = 0.f;
      for (int uu = 0; uu < 64; ++uu) acc += m[64 + uu * 3 + i2] * l2w1[uu * 32 + w];
      soW[wv][64 + q] = acc * scl + sc[(size_t)n * 160 + 64 + q];
    }
  }
  __syncthreads();

  if (valid) {
#pragma unroll
    for (int p = 0; p < 2; ++p) {
      const int c = p * 64 + l;
      float val;
      if (c < 32) {
        val = silu(soW[wv][c]);
      } else {
        const int q = c - 32, w = q / 3, i2 = q - 3 * w;
        val = silu(soW[wv][32 + w]) * soW[wv][64 + w * 3 + i2];
      }
      out[(size_t)n * 128 + c] = nf[(size_t)n * 128 + c] + val;
    }
  }
}

extern "C" void kernel_launch(void* const* d_in, const int* in_sizes, int n_in,
                              void* d_out, int out_size, void* d_ws, size_t ws_size,
                              hipStream_t stream)
{
  const float* nf    = (const float*)d_in[0];
  const float* na    = (const float*)d_in[1];
  const float* eattr = (const float*)d_in[2];
  const float* eemb  = (const float*)d_in[3];
  const float* l1w0  = (const float*)d_in[4];
  const float* l1w1  = (const float*)d_in[5];
  const float* fw1   = (const float*)d_in[6];
  const float* fw2   = (const float*)d_in[7];
  const float* fw3   = (const float*)d_in[8];
  const float* l2w0  = (const float*)d_in[9];
  const float* l2w1  = (const float*)d_in[10];
  const float* scw0  = (const float*)d_in[11];
  const float* scw1  = (const float*)d_in[12];
  const int*   eidx  = (const int*)d_in[13];
  const int*   avgp  = (const int*)d_in[14];

  const int N = in_sizes[0] / 128;
  const int E = in_sizes[2] / 4;

  // Same footprint as R3-R19: wbuf region (E*128 floats) holds bf16 wbuf
  // (first E*64 floats) + slot-ordered srcS (E ints) + eaS (E float4).
  float* y       = (float*)d_ws;                    // N*128
  float* sc      = y + (size_t)N * 128;             // N*160
  float* wbuff   = sc + (size_t)N * 160;            // E*128 floats reserved
  unsigned short* wbuf = (unsigned short*)wbuff;    // E*128 bf16 (= E*64 floats)
  int*    srcS   = (int*)(wbuff + (size_t)E * 64);  // E ints
  float4* eaS    = (float4*)(wbuff + (size_t)E * 64 + E);  // E float4 (16B-aligned)
  int*   counts  = (int*)(wbuff + (size_t)E * 128); // N
  int*   offsets = counts + N;                      // N+1
  int*   cursor  = offsets + N + 1;                 // N
  int*   elist   = cursor + N;                      // E (slot -> eid)

  hipMemsetAsync(counts, 0, (size_t)N * sizeof(int), stream);
  node_pre_kernel<<<(N + 31) / 32, 256, 0, stream>>>(nf, na, l1w0, l1w1, scw0, scw1, y, sc, N);
  hist_kernel<<<(E + 255) / 256, 256, 0, stream>>>(eidx, counts, E);
  scan_kernel<<<1, 1024, 0, stream>>>(counts, offsets, cursor, N);
  scatter_kernel<<<(E + 255) / 256, 256, 0, stream>>>(eidx, eattr, cursor, elist, srcS, eaS, E);
  edge_mlp_kernel<<<(E + 127) / 128, 256, 0, stream>>>(eemb, fw1, fw2, fw3, elist, wbuf, E);
  gather_out_kernel<<<(N + 3) / 4, 256, 0, stream>>>(nf, wbuf, y, sc, l2w0, l2w1,
                                                     offsets, srcS, eaS, avgp,
                                                     (float*)d_out, N, E);
}

// Round 21
// 207.709 us; speedup vs baseline: 1.0135x; 1.0006x over previous
//
#include <hip/hip_runtime.h>
#include <math.h>

__device__ __forceinline__ float silu(float x) { return x / (1.0f + __expf(-x)); }

typedef __attribute__((ext_vector_type(8))) short short8v;  // 8 bf16 (4 VGPRs)
typedef __attribute__((ext_vector_type(4))) float f32x4;

__device__ __forceinline__ unsigned short f2bf(float x) {
  unsigned int u = __float_as_uint(x);
  return (unsigned short)((u + 0x8000u) >> 16);
}

// ---------------- Kernel 1: node precompute via bf16 MFMA ------------------
// y written INTERLEAVED for gather: yg[n][u*4 + {0,1,2,3}] = {g0, g1x, g1y, g1z}
__global__ __launch_bounds__(256) void node_pre_kernel(
    const float* __restrict__ nf, const float* __restrict__ na,
    const float* __restrict__ w0, const float* __restrict__ w1,
    const float* __restrict__ scw0, const float* __restrict__ scw1,
    float* __restrict__ y, float* __restrict__ sc, int N)
{
  __shared__ float nfL[32][132];
  __shared__ __align__(16) char aB[4096];
  __shared__ __align__(16) char wB[32768];
  const int t = threadIdx.x;
  const int n0 = blockIdx.x * 32;
  const int wv = t >> 6, l = t & 63;
  const int lrow = l & 15, lkg = l >> 4;
  const int ann = t >> 3, ac = t & 7;
  const float inv_sqrt32 = 0.17677669529663687f;
  const float sc_norm    = 0.08838834764831843f;  // 1/sqrt(32*4)

  for (int x4 = t; x4 < 1024; x4 += 256) {
    const int nn = x4 >> 5, c4 = x4 & 31;
    const int n = n0 + nn;
    float4 v = make_float4(0.f, 0.f, 0.f, 0.f);
    if (n < N) v = *(const float4*)(nf + (size_t)n * 128 + c4 * 4);
    *(float4*)&nfL[nn][c4 * 4] = v;
  }
  if (t < 128) {
    const int nn = t >> 2, c = t & 3;
    const int n = n0 + nn;
    nfL[nn][128 + c] = (n < N) ? na[(size_t)n * 4 + c] : 0.f;
  }
  for (int x = t; x < 1024; x += 256) {
    const int u = x >> 5, w = x & 31;
    *(unsigned short*)(wB + 0 + w * 128 + (((u >> 3) ^ (w & 7)) * 16) + (u & 7) * 2) = f2bf(w0[x]);
  }
  for (int x = t; x < 1024; x += 256) {
    const int u = x >> 5, w = x & 31;
    *(unsigned short*)(wB + 4096 + w * 128 + (((u >> 3) ^ (w & 7)) * 16) + (u & 7) * 2) = f2bf(w1[x]);
  }
  for (int x = t; x < 8192; x += 256) {
    const int k = x >> 6, c = x & 63;
    const int half = k >> 6, kk = k & 63;
    *(unsigned short*)(wB + 8192 + half * 8192 + c * 128 + (((kk >> 3) ^ (c & 7)) * 16) + (kk & 7) * 2) = f2bf(scw0[x]);
  }
  for (int x = t; x < 4096; x += 256) {
    const int k = x >> 5, c = x & 31;
    const int half = k >> 6, kk = k & 63;
    *(unsigned short*)(wB + 24576 + half * 4096 + c * 128 + (((kk >> 3) ^ (c & 7)) * 16) + (kk & 7) * 2) = f2bf(scw1[x]);
  }
  __syncthreads();

  // lin1 y0 -> yg[n][w*4 + 0]
  if (ac < 4) {
    short8v hv;
#pragma unroll
    for (int j = 0; j < 8; ++j) hv[j] = (short)f2bf(nfL[ann][ac * 8 + j]);
    *(short8v*)(aB + ann * 128 + ((ac ^ (ann & 7)) * 16)) = hv;
  }
  __syncthreads();
  {
    const int mt = wv >> 1, nt = wv & 1;
    const int ar = mt * 16 + lrow, br = nt * 16 + lrow;
    const short8v A = *(const short8v*)(aB + ar * 128 + ((lkg ^ (ar & 7)) * 16));
    const short8v B = *(const short8v*)(wB + 0 + br * 128 + ((lkg ^ (br & 7)) * 16));
    f32x4 acc = (f32x4){0.f, 0.f, 0.f, 0.f};
    acc = __builtin_amdgcn_mfma_f32_16x16x32_bf16(A, B, acc, 0, 0, 0);
#pragma unroll
    for (int r = 0; r < 4; ++r) {
      const int nn = mt * 16 + lkg * 4 + r;
      const int n = n0 + nn;
      if (n < N) y[(size_t)n * 128 + (nt * 16 + lrow) * 4] = acc[r] * inv_sqrt32;
    }
  }
  __syncthreads();

  // lin1 y1 comp i -> yg[n][w*4 + 1 + i]
  for (int i = 0; i < 3; ++i) {
    if (ac < 4) {
      short8v hv;
#pragma unroll
      for (int j = 0; j < 8; ++j)
        hv[j] = (short)f2bf(nfL[ann][32 + (ac * 8 + j) * 3 + i]);
      *(short8v*)(aB + ann * 128 + ((ac ^ (ann & 7)) * 16)) = hv;
    }
    __syncthreads();
    {
      const int mt = wv >> 1, nt = wv & 1;
      const int ar = mt * 16 + lrow, br = nt * 16 + lrow;
      const short8v A = *(const short8v*)(aB + ar * 128 + ((lkg ^ (ar & 7)) * 16));
      const short8v B = *(const short8v*)(wB + 4096 + br * 128 + ((lkg ^ (br & 7)) * 16));
      f32x4 acc = (f32x4){0.f, 0.f, 0.f, 0.f};
      acc = __builtin_amdgcn_mfma_f32_16x16x32_bf16(A, B, acc, 0, 0, 0);
#pragma unroll
      for (int r = 0; r < 4; ++r) {
        const int nn = mt * 16 + lkg * 4 + r;
        const int n = n0 + nn;
        if (n < N) y[(size_t)n * 128 + (nt * 16 + lrow) * 4 + 1 + i] = acc[r] * inv_sqrt32;
      }
    }
    __syncthreads();
  }

  {
    f32x4 accS[2] = {(f32x4){0.f,0.f,0.f,0.f}, (f32x4){0.f,0.f,0.f,0.f}};
    const int mt = wv & 1, ntb = (wv >> 1) * 2;
#pragma unroll
    for (int half = 0; half < 2; ++half) {
      {
        short8v hv;
#pragma unroll
        for (int j = 0; j < 8; ++j) {
          const int k = half * 64 + ac * 8 + j;
          hv[j] = (short)f2bf(nfL[ann][k >> 2] * nfL[ann][128 + (k & 3)]);
        }
        *(short8v*)(aB + ann * 128 + ((ac ^ (ann & 7)) * 16)) = hv;
      }
      __syncthreads();
#pragma unroll
      for (int step = 0; step < 2; ++step) {
        const int ar = mt * 16 + lrow;
        const short8v A = *(const short8v*)(aB + ar * 128 + (((step * 4 + lkg) ^ (ar & 7)) * 16));
#pragma unroll
        for (int q = 0; q < 2; ++q) {
          const int br = (ntb + q) * 16 + lrow;
          const short8v B = *(const short8v*)(wB + 8192 + half * 8192 + br * 128 + (((step * 4 + lkg) ^ (br & 7)) * 16));
          accS[q] = __builtin_amdgcn_mfma_f32_16x16x32_bf16(A, B, accS[q], 0, 0, 0);
        }
      }
      __syncthreads();
    }
#pragma unroll
    for (int q = 0; q < 2; ++q) {
#pragma unroll
      for (int r = 0; r < 4; ++r) {
        const int nn = mt * 16 + lkg * 4 + r;
        const int n = n0 + nn;
        if (n < N) sc[(size_t)n * 160 + (ntb + q) * 16 + lrow] = accS[q][r] * sc_norm;
      }
    }
  }

  for (int i = 0; i < 3; ++i) {
    f32x4 acc = (f32x4){0.f, 0.f, 0.f, 0.f};
    const int mt = wv >> 1, nt = wv & 1;
#pragma unroll
    for (int half = 0; half < 2; ++half) {
      {
        short8v hv;
#pragma unroll
        for (int j = 0; j < 8; ++j) {
          const int k = half * 64 + ac * 8 + j;
          hv[j] = (short)f2bf(nfL[ann][32 + (k >> 2) * 3 + i] * nfL[ann][128 + (k & 3)]);
        }
        *(short8v*)(aB + ann * 128 + ((ac ^ (ann & 7)) * 16)) = hv;
      }
      __syncthreads();
#pragma unroll
      for (int step = 0; step < 2; ++step) {
        const int ar = mt * 16 + lrow;
        const short8v A = *(const short8v*)(aB + ar * 128 + (((step * 4 + lkg) ^ (ar & 7)) * 16));
        const int br = nt * 16 + lrow;
        const short8v B = *(const short8v*)(wB + 24576 + half * 4096 + br * 128 + (((step * 4 + lkg) ^ (br & 7)) * 16));
        acc = __builtin_amdgcn_mfma_f32_16x16x32_bf16(A, B, acc, 0, 0, 0);
      }
      __syncthreads();
    }
#pragma unroll
    for (int r = 0; r < 4; ++r) {
      const int nn = mt * 16 + lkg * 4 + r;
      const int n = n0 + nn;
      if (n < N) sc[(size_t)n * 160 + 64 + (nt * 16 + lrow) * 3 + i] = acc[r] * sc_norm;
    }
  }
}

// ---------------- CSR build ----------------
__global__ __launch_bounds__(256) void hist_kernel(const int* __restrict__ eidx,
                                                   int* __restrict__ counts, int E)
{
  const int e = blockIdx.x * 256 + threadIdx.x;
  if (e < E) atomicAdd(&counts[eidx[E + e]], 1);
}

__global__ __launch_bounds__(1024) void scan_kernel(const int* __restrict__ counts,
                                                    int* __restrict__ offsets,
                                                    int* __restrict__ cursor, int N)
{
  __shared__ int part[1024];
  const int t = threadIdx.x;
  const int per = (N + 1023) / 1024;
  const int base = t * per;
  int s = 0;
  for (int k = 0; k < per; ++k) { int idx = base + k; if (idx < N) s += counts[idx]; }
  part[t] = s;
  __syncthreads();
  for (int off = 1; off < 1024; off <<= 1) {
    int v = part[t];
    if (t >= off) v += part[t - off];
    __syncthreads();
    part[t] = v;
    __syncthreads();
  }
  int run = (t == 0) ? 0 : part[t - 1];
  for (int k = 0; k < per; ++k) {
    int idx = base + k;
    if (idx < N) { offsets[idx] = run; cursor[idx] = run; run += counts[idx]; }
  }
  if (t == 1023) offsets[N] = run;
}

__global__ __launch_bounds__(256) void scatter_kernel(
    const int* __restrict__ eidx, const float* __restrict__ eattr,
    int* __restrict__ cursor, int* __restrict__ elist,
    int* __restrict__ srcS, float4* __restrict__ eaS, int E)
{
  const int e = blockIdx.x * 256 + threadIdx.x;
  if (e >= E) return;
  const int dst = eidx[E + e];
  const int slot = atomicAdd(&cursor[dst], 1);
  elist[slot] = e;
  srcS[slot] = eidx[e];
  eaS[slot] = *(const float4*)(eattr + (size_t)e * 4);
}

// ---------------- Kernel 2: FUSED edge MLP; layers 2+3 via MFMA; bf16 out --
// wbuf layout INTERLEAVED: [slot][u][4] = {w00,w01,w10,w11} per u (u<32).
__global__ __launch_bounds__(256) void edge_mlp_kernel(
    const float* __restrict__ eemb, const float* __restrict__ fw1,
    const float* __restrict__ fw2, const float* __restrict__ fw3,
    const int* __restrict__ elist, unsigned short* __restrict__ wbuf, int E)
{
  __shared__ __align__(16) float w1L[512];     // [k<64][r<8] transposed, f32
  __shared__ __align__(16) char reg1[16384];
  __shared__ __align__(16) char reg2[32768];
  const int t = threadIdx.x;
  const int base = blockIdx.x * 128;

  for (int x = t; x < 512; x += 256)  w1L[x] = fw1[(x & 7) * 64 + (x >> 3)];
  for (int x = t; x < 4096; x += 256) {
    const int k = x >> 6, o = x & 63;
    *(unsigned short*)(reg2 + o * 128 + (((k >> 3) ^ (o & 7)) * 16) + (k & 7) * 2) = f2bf(fw2[x]);
  }

  const int e = t & 127, kg = t >> 7;
  {
    const int slot0 = base + e;
    const int eid = (slot0 < E) ? elist[slot0] : 0;
    const float4 em0 = *(const float4*)(eemb + (size_t)eid * 8);
    const float4 em1 = *(const float4*)(eemb + (size_t)eid * 8 + 4);
    __syncthreads();

    const float inv_sqrt8 = 0.35355339059327373f;
#pragma unroll
    for (int c = 0; c < 4; ++c) {
      short8v hv;
#pragma unroll
      for (int j = 0; j < 8; ++j) {
        const int k = kg * 32 + c * 8 + j;
        const float4 wa = *(const float4*)(w1L + k * 8);
        const float4 wb = *(const float4*)(w1L + k * 8 + 4);
        const float a = em0.x * wa.x + em0.y * wa.y + em0.z * wa.z + em0.w * wa.w
                      + em1.x * wb.x + em1.y * wb.y + em1.z * wb.z + em1.w * wb.w;
        hv[j] = (short)f2bf(silu(a * inv_sqrt8));
      }
      const int cc = kg * 4 + c;
      *(short8v*)(reg1 + e * 128 + ((cc ^ (e & 7)) * 16)) = hv;
    }
  }
  __syncthreads();

  const int wv = t >> 6, l = t & 63;
  const int lrow = l & 15, lkg = l >> 4;

  {
    f32x4 accB[2][4];
#pragma unroll
    for (int mt = 0; mt < 2; ++mt)
#pragma unroll
      for (int nt = 0; nt < 4; ++nt)
        accB[mt][nt] = (f32x4){0.f, 0.f, 0.f, 0.f};

#pragma unroll
    for (int step = 0; step < 2; ++step) {
#pragma unroll
      for (int mt = 0; mt < 2; ++mt) {
        const int ea = wv * 32 + mt * 16 + lrow;
        const short8v A = *(const short8v*)(reg1 + ea * 128 + (((step * 4 + lkg) ^ (ea & 7)) * 16));
#pragma unroll
        for (int nt = 0; nt < 4; ++nt) {
          const int o = nt * 16 + lrow;
          const short8v B = *(const short8v*)(reg2 + o * 128 + (((step * 4 + lkg) ^ (o & 7)) * 16));
          accB[mt][nt] = __builtin_amdgcn_mfma_f32_16x16x32_bf16(A, B, accB[mt][nt], 0, 0, 0);
        }
      }
    }
    __syncthreads();

#pragma unroll
    for (int mt = 0; mt < 2; ++mt) {
#pragma unroll
      for (int r = 0; r < 4; ++r) {
        const int eo = wv * 32 + mt * 16 + lkg * 4 + r;
#pragma unroll
        for (int nt = 0; nt < 4; ++nt) {
          const int o = nt * 16 + lrow;
          const float val = silu(accB[mt][nt][r] * 0.125f);
          *(unsigned short*)(reg1 + eo * 128 + (((o >> 3) ^ (eo & 7)) * 16) + (o & 7) * 2) = f2bf(val);
        }
      }
    }
  }
  for (int x = t; x < 8192; x += 256) {
    const int k = x >> 7, c = x & 127;
    *(unsigned short*)(reg2 + c * 128 + (((k >> 3) ^ (c & 7)) * 16) + (k & 7) * 2) = f2bf(fw3[x]);
  }
  __syncthreads();

  {
    f32x4 accd[2][8];
#pragma unroll
    for (int mt = 0; mt < 2; ++mt)
#pragma unroll
      for (int nt = 0; nt < 8; ++nt)
        accd[mt][nt] = (f32x4){0.f, 0.f, 0.f, 0.f};

#pragma unroll
    for (int step = 0; step < 2; ++step) {
      const int ea0 = wv * 32 + lrow;
      const int ea1 = wv * 32 + 16 + lrow;
      const short8v A0 = *(const short8v*)(reg1 + ea0 * 128 + (((step * 4 + lkg) ^ (ea0 & 7)) * 16));
      const short8v A1 = *(const short8v*)(reg1 + ea1 * 128 + (((step * 4 + lkg) ^ (ea1 & 7)) * 16));
#pragma unroll
      for (int nt = 0; nt < 8; ++nt) {
        const int n = nt * 16 + lrow;
        const short8v B = *(const short8v*)(reg2 + n * 128 + (((step * 4 + lkg) ^ (n & 7)) * 16));
        accd[0][nt] = __builtin_amdgcn_mfma_f32_16x16x32_bf16(A0, B, accd[0][nt], 0, 0, 0);
        accd[1][nt] = __builtin_amdgcn_mfma_f32_16x16x32_bf16(A1, B, accd[1][nt], 0, 0, 0);
      }
    }
#pragma unroll
    for (int mt = 0; mt < 2; ++mt) {
#pragma unroll
      for (int r = 0; r < 4; ++r) {
        const int eo = wv * 32 + mt * 16 + lkg * 4 + r;
        const int slot = base + eo;
        if (slot < E) {
          unsigned short* wrow = wbuf + (size_t)slot * 128;
#pragma unroll
          for (int nt = 0; nt < 8; ++nt) {
            const int uu = (nt & 1) * 16 + lrow;
            const int comp = nt >> 1;
            wrow[uu * 4 + comp] = f2bf(accd[mt][nt][r] * 0.125f);
          }
        }
      }
    }
  }
}

// ---------------- Kernel 3: wave-per-node gather, float4 y, chunked --------
__global__ __launch_bounds__(256) void gather_out_kernel(
    const float* __restrict__ nf, const unsigned short* __restrict__ wbuf,
    const float* __restrict__ y, const float* __restrict__ sc,
    const float* __restrict__ l2w0, const float* __restrict__ l2w1,
    const int* __restrict__ offsets, const int* __restrict__ srcS,
    const float4* __restrict__ eaS,
    const int* __restrict__ avgp, float* __restrict__ out, int N, int E)
{
  __shared__ float mW[4][264];    // per-wave m[256] (+pad)
  __shared__ float soW[4][160];   // per-wave so0[64] + so1[96]
  const int t = threadIdx.x;
  const int wv = t >> 6, l = t & 63;
  const int n = blockIdx.x * 4 + wv;
  const bool valid = (n < N);
  const int u = l & 31, half = l >> 5;

  const int beg = valid ? offsets[n] : 0;
  const int end = valid ? offsets[n + 1] : 0;
  const int s0 = beg + half;
  const int cnt = (s0 < end) ? ((end - s0 + 1) >> 1) : 0;

  float a_s0 = 0.f, a_s1 = 0.f;
  float v0x = 0.f, v0y = 0.f, v0z = 0.f;
  float v1x = 0.f, v1y = 0.f, v1z = 0.f;

  int i = 0;
  for (; i + 4 <= cnt; i += 4) {
    int csrc[4]; float4 cea[4]; uint2 cw[4];
#pragma unroll
    for (int q = 0; q < 4; ++q) {
      const int sq = s0 + 2 * (i + q);
      csrc[q] = srcS[sq];
      cea[q]  = eaS[sq];
      cw[q]   = *(const uint2*)(wbuf + (size_t)sq * 128 + u * 4);
    }
    float4 cg[4];
#pragma unroll
    for (int q = 0; q < 4; ++q)
      cg[q] = *(const float4*)(y + (size_t)csrc[q] * 128 + u * 4);
#pragma unroll
    for (int q = 0; q < 4; ++q) {
      const float w00 = __uint_as_float(cw[q].x << 16);
      const float w01 = __uint_as_float(cw[q].x & 0xffff0000u);
      const float w10 = __uint_as_float(cw[q].y << 16);
      const float w11 = __uint_as_float(cw[q].y & 0xffff0000u);
      a_s0 += w00 * cg[q].x * cea[q].x;
      const float t01 = w01 * cg[q].x;
      v0x += t01 * cea[q].y; v0y += t01 * cea[q].z; v0z += t01 * cea[q].w;
      const float wg = w10 * cea[q].x;
      v1x += wg * cg[q].y; v1y += wg * cg[q].z; v1z += wg * cg[q].w;
      a_s1 += w11 * (cg[q].y * cea[q].y + cg[q].z * cea[q].z + cg[q].w * cea[q].w);
    }
  }
  for (; i < cnt; ++i) {
    const int sq = s0 + 2 * i;
    const int src = srcS[sq];
    const float4 ea = eaS[sq];
    const uint2 wr = *(const uint2*)(wbuf + (size_t)sq * 128 + u * 4);
    const float4 g = *(const float4*)(y + (size_t)src * 128 + u * 4);
    const float w00 = __uint_as_float(wr.x << 16);
    const float w01 = __uint_as_float(wr.x & 0xffff0000u);
    const float w10 = __uint_as_float(wr.y << 16);
    const float w11 = __uint_as_float(wr.y & 0xffff0000u);
    a_s0 += w00 * g.x * ea.x;
    const float t01 = w01 * g.x;
    v0x += t01 * ea.y; v0y += t01 * ea.z; v0z += t01 * ea.w;
    const float wg = w10 * ea.x;
    v1x += wg * g.y; v1y += wg * g.z; v1z += wg * g.w;
    a_s1 += w11 * (g.y * ea.y + g.z * ea.z + g.w * ea.w);
  }

  a_s0 += __shfl_xor(a_s0, 32);  a_s1 += __shfl_xor(a_s1, 32);
  v0x += __shfl_xor(v0x, 32); v0y += __shfl_xor(v0y, 32); v0z += __shfl_xor(v0z, 32);
  v1x += __shfl_xor(v1x, 32); v1y += __shfl_xor(v1y, 32); v1z += __shfl_xor(v1z, 32);
  if (half == 0) {
    mW[wv][u]          = a_s0;
    mW[wv][32 + u]     = a_s1 * 0.5773502691896258f;
    mW[wv][64 + 3 * u] = v0x; mW[wv][65 + 3 * u] = v0y; mW[wv][66 + 3 * u] = v0z;
    mW[wv][160 + 3 * u] = v1x; mW[wv][161 + 3 * u] = v1y; mW[wv][162 + 3 * u] = v1z;
  }
  __syncthreads();

  const float scl = 0.125f * rsqrtf((float)(*avgp));
  const float* m = mW[wv];
  if (valid) {
    {
      float acc = 0.f;
      for (int uu = 0; uu < 64; ++uu) acc += m[uu] * l2w0[uu * 64 + l];
      soW[wv][l] = acc * scl + sc[(size_t)n * 160 + l];
    }
    {
      const int w = l / 3, i2 = l - 3 * w;
      float acc = 0.f;
      for (int uu = 0; uu < 64; ++uu) acc += m[64 + uu * 3 + i2] * l2w1[uu * 32 + w];
      soW[wv][64 + l] = acc * scl + sc[(size_t)n * 160 + 64 + l];
    }
    if (l < 32) {
      const int q = 64 + l, w = q / 3, i2 = q - 3 * w;
      float acc = 0.f;
      for (int uu = 0; uu < 64; ++uu) acc += m[64 + uu * 3 + i2] * l2w1[uu * 32 + w];
      soW[wv][64 + q] = acc * scl + sc[(size_t)n * 160 + 64 + q];
    }
  }
  __syncthreads();

  if (valid) {
#pragma unroll
    for (int p = 0; p < 2; ++p) {
      const int c = p * 64 + l;
      float val;
      if (c < 32) {
        val = silu(soW[wv][c]);
      } else {
        const int q = c - 32, w = q / 3, i2 = q - 3 * w;
        val = silu(soW[wv][32 + w]) * soW[wv][64 + w * 3 + i2];
      }
      out[(size_t)n * 128 + c] = nf[(size_t)n * 128 + c] + val;
    }
  }
}

extern "C" void kernel_launch(void* const* d_in, const int* in_sizes, int n_in,
                              void* d_out, int out_size, void* d_ws, size_t ws_size,
                              hipStream_t stream)
{
  const float* nf    = (const float*)d_in[0];
  const float* na    = (const float*)d_in[1];
  const float* eattr = (const float*)d_in[2];
  const float* eemb  = (const float*)d_in[3];
  const float* l1w0  = (const float*)d_in[4];
  const float* l1w1  = (const float*)d_in[5];
  const float* fw1   = (const float*)d_in[6];
  const float* fw2   = (const float*)d_in[7];
  const float* fw3   = (const float*)d_in[8];
  const float* l2w0  = (const float*)d_in[9];
  const float* l2w1  = (const float*)d_in[10];
  const float* scw0  = (const float*)d_in[11];
  const float* scw1  = (const float*)d_in[12];
  const int*   eidx  = (const int*)d_in[13];
  const int*   avgp  = (const int*)d_in[14];

  const int N = in_sizes[0] / 128;
  const int E = in_sizes[2] / 4;

  float* y       = (float*)d_ws;                    // N*128 (interleaved g layout)
  float* sc      = y + (size_t)N * 128;             // N*160
  float* wbuff   = sc + (size_t)N * 160;            // E*128 floats reserved
  unsigned short* wbuf = (unsigned short*)wbuff;    // E*128 bf16 (= E*64 floats)
  int*    srcS   = (int*)(wbuff + (size_t)E * 64);  // E ints
  float4* eaS    = (float4*)(wbuff + (size_t)E * 64 + E);  // E float4
  int*   counts  = (int*)(wbuff + (size_t)E * 128); // N
  int*   offsets = counts + N;                      // N+1
  int*   cursor  = offsets + N + 1;                 // N
  int*   elist   = cursor + N;                      // E

  hipMemsetAsync(counts, 0, (size_t)N * sizeof(int), stream);
  node_pre_kernel<<<(N + 31) / 32, 256, 0, stream>>>(nf, na, l1w0, l1w1, scw0, scw1, y, sc, N);
  hist_kernel<<<(E + 255) / 256, 256, 0, stream>>>(eidx, counts, E);
  scan_kernel<<<1, 1024, 0, stream>>>(counts, offsets, cursor, N);
  scatter_kernel<<<(E + 255) / 256, 256, 0, stream>>>(eidx, eattr, cursor, elist, srcS, eaS, E);
  edge_mlp_kernel<<<(E + 127) / 128, 256, 0, stream>>>(eemb, fw1, fw2, fw3, elist, wbuf, E);
  gather_out_kernel<<<(N + 3) / 4, 256, 0, stream>>>(nf, wbuf, y, sc, l2w0, l2w1,
                                                     offsets, srcS, eaS, avgp,
                                                     (float*)d_out, N, E);
}

// Round 22
// 204.825 us; speedup vs baseline: 1.0278x; 1.0141x over previous
//
#include <hip/hip_runtime.h>
#include <math.h>

__device__ __forceinline__ float silu(float x) { return x / (1.0f + __expf(-x)); }

typedef __attribute__((ext_vector_type(8))) short short8v;  // 8 bf16 (4 VGPRs)
typedef __attribute__((ext_vector_type(4))) float f32x4;

__device__ __forceinline__ unsigned short f2bf(float x) {
  unsigned int u = __float_as_uint(x);
  return (unsigned short)((u + 0x8000u) >> 16);
}

// ---------------- Kernel 1: node precompute via bf16 MFMA ------------------
// y stored bf16 INTERLEAVED: yb[n][u*4 + {0,1,2,3}] = {g0, g1x, g1y, g1z}
__global__ __launch_bounds__(256) void node_pre_kernel(
    const float* __restrict__ nf, const float* __restrict__ na,
    const float* __restrict__ w0, const float* __restrict__ w1,
    const float* __restrict__ scw0, const float* __restrict__ scw1,
    unsigned short* __restrict__ yb, float* __restrict__ sc, int N)
{
  __shared__ float nfL[32][132];
  __shared__ __align__(16) char aB[4096];
  __shared__ __align__(16) char wB[32768];
  const int t = threadIdx.x;
  const int n0 = blockIdx.x * 32;
  const int wv = t >> 6, l = t & 63;
  const int lrow = l & 15, lkg = l >> 4;
  const int ann = t >> 3, ac = t & 7;
  const float inv_sqrt32 = 0.17677669529663687f;
  const float sc_norm    = 0.08838834764831843f;  // 1/sqrt(32*4)

  for (int x4 = t; x4 < 1024; x4 += 256) {
    const int nn = x4 >> 5, c4 = x4 & 31;
    const int n = n0 + nn;
    float4 v = make_float4(0.f, 0.f, 0.f, 0.f);
    if (n < N) v = *(const float4*)(nf + (size_t)n * 128 + c4 * 4);
    *(float4*)&nfL[nn][c4 * 4] = v;
  }
  if (t < 128) {
    const int nn = t >> 2, c = t & 3;
    const int n = n0 + nn;
    nfL[nn][128 + c] = (n < N) ? na[(size_t)n * 4 + c] : 0.f;
  }
  for (int x = t; x < 1024; x += 256) {
    const int u = x >> 5, w = x & 31;
    *(unsigned short*)(wB + 0 + w * 128 + (((u >> 3) ^ (w & 7)) * 16) + (u & 7) * 2) = f2bf(w0[x]);
  }
  for (int x = t; x < 1024; x += 256) {
    const int u = x >> 5, w = x & 31;
    *(unsigned short*)(wB + 4096 + w * 128 + (((u >> 3) ^ (w & 7)) * 16) + (u & 7) * 2) = f2bf(w1[x]);
  }
  for (int x = t; x < 8192; x += 256) {
    const int k = x >> 6, c = x & 63;
    const int half = k >> 6, kk = k & 63;
    *(unsigned short*)(wB + 8192 + half * 8192 + c * 128 + (((kk >> 3) ^ (c & 7)) * 16) + (kk & 7) * 2) = f2bf(scw0[x]);
  }
  for (int x = t; x < 4096; x += 256) {
    const int k = x >> 5, c = x & 31;
    const int half = k >> 6, kk = k & 63;
    *(unsigned short*)(wB + 24576 + half * 4096 + c * 128 + (((kk >> 3) ^ (c & 7)) * 16) + (kk & 7) * 2) = f2bf(scw1[x]);
  }
  __syncthreads();

  // lin1 y0 -> yb[n][w*4 + 0]
  if (ac < 4) {
    short8v hv;
#pragma unroll
    for (int j = 0; j < 8; ++j) hv[j] = (short)f2bf(nfL[ann][ac * 8 + j]);
    *(short8v*)(aB + ann * 128 + ((ac ^ (ann & 7)) * 16)) = hv;
  }
  __syncthreads();
  {
    const int mt = wv >> 1, nt = wv & 1;
    const int ar = mt * 16 + lrow, br = nt * 16 + lrow;
    const short8v A = *(const short8v*)(aB + ar * 128 + ((lkg ^ (ar & 7)) * 16));
    const short8v B = *(const short8v*)(wB + 0 + br * 128 + ((lkg ^ (br & 7)) * 16));
    f32x4 acc = (f32x4){0.f, 0.f, 0.f, 0.f};
    acc = __builtin_amdgcn_mfma_f32_16x16x32_bf16(A, B, acc, 0, 0, 0);
#pragma unroll
    for (int r = 0; r < 4; ++r) {
      const int nn = mt * 16 + lkg * 4 + r;
      const int n = n0 + nn;
      if (n < N) yb[(size_t)n * 128 + (nt * 16 + lrow) * 4] = f2bf(acc[r] * inv_sqrt32);
    }
  }
  __syncthreads();

  // lin1 y1 comp i -> yb[n][w*4 + 1 + i]
  for (int i = 0; i < 3; ++i) {
    if (ac < 4) {
      short8v hv;
#pragma unroll
      for (int j = 0; j < 8; ++j)
        hv[j] = (short)f2bf(nfL[ann][32 + (ac * 8 + j) * 3 + i]);
      *(short8v*)(aB + ann * 128 + ((ac ^ (ann & 7)) * 16)) = hv;
    }
    __syncthreads();
    {
      const int mt = wv >> 1, nt = wv & 1;
      const int ar = mt * 16 + lrow, br = nt * 16 + lrow;
      const short8v A = *(const short8v*)(aB + ar * 128 + ((lkg ^ (ar & 7)) * 16));
      const short8v B = *(const short8v*)(wB + 4096 + br * 128 + ((lkg ^ (br & 7)) * 16));
      f32x4 acc = (f32x4){0.f, 0.f, 0.f, 0.f};
      acc = __builtin_amdgcn_mfma_f32_16x16x32_bf16(A, B, acc, 0, 0, 0);
#pragma unroll
      for (int r = 0; r < 4; ++r) {
        const int nn = mt * 16 + lkg * 4 + r;
        const int n = n0 + nn;
        if (n < N) yb[(size_t)n * 128 + (nt * 16 + lrow) * 4 + 1 + i] = f2bf(acc[r] * inv_sqrt32);
      }
    }
    __syncthreads();
  }

  {
    f32x4 accS[2] = {(f32x4){0.f,0.f,0.f,0.f}, (f32x4){0.f,0.f,0.f,0.f}};
    const int mt = wv & 1, ntb = (wv >> 1) * 2;
#pragma unroll
    for (int half = 0; half < 2; ++half) {
      {
        short8v hv;
#pragma unroll
        for (int j = 0; j < 8; ++j) {
          const int k = half * 64 + ac * 8 + j;
          hv[j] = (short)f2bf(nfL[ann][k >> 2] * nfL[ann][128 + (k & 3)]);
        }
        *(short8v*)(aB + ann * 128 + ((ac ^ (ann & 7)) * 16)) = hv;
      }
      __syncthreads();
#pragma unroll
      for (int step = 0; step < 2; ++step) {
        const int ar = mt * 16 + lrow;
        const short8v A = *(const short8v*)(aB + ar * 128 + (((step * 4 + lkg) ^ (ar & 7)) * 16));
#pragma unroll
        for (int q = 0; q < 2; ++q) {
          const int br = (ntb + q) * 16 + lrow;
          const short8v B = *(const short8v*)(wB + 8192 + half * 8192 + br * 128 + (((step * 4 + lkg) ^ (br & 7)) * 16));
          accS[q] = __builtin_amdgcn_mfma_f32_16x16x32_bf16(A, B, accS[q], 0, 0, 0);
        }
      }
      __syncthreads();
    }
#pragma unroll
    for (int q = 0; q < 2; ++q) {
#pragma unroll
      for (int r = 0; r < 4; ++r) {
        const int nn = mt * 16 + lkg * 4 + r;
        const int n = n0 + nn;
        if (n < N) sc[(size_t)n * 160 + (ntb + q) * 16 + lrow] = accS[q][r] * sc_norm;
      }
    }
  }

  for (int i = 0; i < 3; ++i) {
    f32x4 acc = (f32x4){0.f, 0.f, 0.f, 0.f};
    const int mt = wv >> 1, nt = wv & 1;
#pragma unroll
    for (int half = 0; half < 2; ++half) {
      {
        short8v hv;
#pragma unroll
        for (int j = 0; j < 8; ++j) {
          const int k = half * 64 + ac * 8 + j;
          hv[j] = (short)f2bf(nfL[ann][32 + (k >> 2) * 3 + i] * nfL[ann][128 + (k & 3)]);
        }
        *(short8v*)(aB + ann * 128 + ((ac ^ (ann & 7)) * 16)) = hv;
      }
      __syncthreads();
#pragma unroll
      for (int step = 0; step < 2; ++step) {
        const int ar = mt * 16 + lrow;
        const short8v A = *(const short8v*)(aB + ar * 128 + (((step * 4 + lkg) ^ (ar & 7)) * 16));
        const int br = nt * 16 + lrow;
        const short8v B = *(const short8v*)(wB + 24576 + half * 4096 + br * 128 + (((step * 4 + lkg) ^ (br & 7)) * 16));
        acc = __builtin_amdgcn_mfma_f32_16x16x32_bf16(A, B, acc, 0, 0, 0);
      }
      __syncthreads();
    }
#pragma unroll
    for (int r = 0; r < 4; ++r) {
      const int nn = mt * 16 + lkg * 4 + r;
      const int n = n0 + nn;
      if (n < N) sc[(size_t)n * 160 + 64 + (nt * 16 + lrow) * 3 + i] = acc[r] * sc_norm;
    }
  }
}

// ---------------- CSR build ----------------
__global__ __launch_bounds__(256) void hist_kernel(const int* __restrict__ eidx,
                                                   int* __restrict__ counts, int E)
{
  const int e = blockIdx.x * 256 + threadIdx.x;
  if (e < E) atomicAdd(&counts[eidx[E + e]], 1);
}

__global__ __launch_bounds__(1024) void scan_kernel(const int* __restrict__ counts,
                                                    int* __restrict__ offsets,
                                                    int* __restrict__ cursor, int N)
{
  __shared__ int part[1024];
  const int t = threadIdx.x;
  const int per = (N + 1023) / 1024;
  const int base = t * per;
  int s = 0;
  for (int k = 0; k < per; ++k) { int idx = base + k; if (idx < N) s += counts[idx]; }
  part[t] = s;
  __syncthreads();
  for (int off = 1; off < 1024; off <<= 1) {
    int v = part[t];
    if (t >= off) v += part[t - off];
    __syncthreads();
    part[t] = v;
    __syncthreads();
  }
  int run = (t == 0) ? 0 : part[t - 1];
  for (int k = 0; k < per; ++k) {
    int idx = base + k;
    if (idx < N) { offsets[idx] = run; cursor[idx] = run; run += counts[idx]; }
  }
  if (t == 1023) offsets[N] = run;
}

__global__ __launch_bounds__(256) void scatter_kernel(
    const int* __restrict__ eidx, const float* __restrict__ eattr,
    int* __restrict__ cursor, int* __restrict__ elist,
    int* __restrict__ srcS, float4* __restrict__ eaS, int E)
{
  const int e = blockIdx.x * 256 + threadIdx.x;
  if (e >= E) return;
  const int dst = eidx[E + e];
  const int slot = atomicAdd(&cursor[dst], 1);
  elist[slot] = e;
  srcS[slot] = eidx[e];
  eaS[slot] = *(const float4*)(eattr + (size_t)e * 4);
}

// ---------------- Kernel 2: FUSED edge MLP; layers 2+3 via MFMA; bf16 out --
// wbuf layout INTERLEAVED: [slot][u][4] = {w00,w01,w10,w11} per u (u<32).
__global__ __launch_bounds__(256) void edge_mlp_kernel(
    const float* __restrict__ eemb, const float* __restrict__ fw1,
    const float* __restrict__ fw2, const float* __restrict__ fw3,
    const int* __restrict__ elist, unsigned short* __restrict__ wbuf, int E)
{
  __shared__ __align__(16) float w1L[512];     // [k<64][r<8] transposed, f32
  __shared__ __align__(16) char reg1[16384];
  __shared__ __align__(16) char reg2[32768];
  const int t = threadIdx.x;
  const int base = blockIdx.x * 128;

  for (int x = t; x < 512; x += 256)  w1L[x] = fw1[(x & 7) * 64 + (x >> 3)];
  for (int x = t; x < 4096; x += 256) {
    const int k = x >> 6, o = x & 63;
    *(unsigned short*)(reg2 + o * 128 + (((k >> 3) ^ (o & 7)) * 16) + (k & 7) * 2) = f2bf(fw2[x]);
  }

  const int e = t & 127, kg = t >> 7;
  {
    const int slot0 = base + e;
    const int eid = (slot0 < E) ? elist[slot0] : 0;
    const float4 em0 = *(const float4*)(eemb + (size_t)eid * 8);
    const float4 em1 = *(const float4*)(eemb + (size_t)eid * 8 + 4);
    __syncthreads();

    const float inv_sqrt8 = 0.35355339059327373f;
#pragma unroll
    for (int c = 0; c < 4; ++c) {
      short8v hv;
#pragma unroll
      for (int j = 0; j < 8; ++j) {
        const int k = kg * 32 + c * 8 + j;
        const float4 wa = *(const float4*)(w1L + k * 8);
        const float4 wb = *(const float4*)(w1L + k * 8 + 4);
        const float a = em0.x * wa.x + em0.y * wa.y + em0.z * wa.z + em0.w * wa.w
                      + em1.x * wb.x + em1.y * wb.y + em1.z * wb.z + em1.w * wb.w;
        hv[j] = (short)f2bf(silu(a * inv_sqrt8));
      }
      const int cc = kg * 4 + c;
      *(short8v*)(reg1 + e * 128 + ((cc ^ (e & 7)) * 16)) = hv;
    }
  }
  __syncthreads();

  const int wv = t >> 6, l = t & 63;
  const int lrow = l & 15, lkg = l >> 4;

  {
    f32x4 accB[2][4];
#pragma unroll
    for (int mt = 0; mt < 2; ++mt)
#pragma unroll
      for (int nt = 0; nt < 4; ++nt)
        accB[mt][nt] = (f32x4){0.f, 0.f, 0.f, 0.f};

#pragma unroll
    for (int step = 0; step < 2; ++step) {
#pragma unroll
      for (int mt = 0; mt < 2; ++mt) {
        const int ea = wv * 32 + mt * 16 + lrow;
        const short8v A = *(const short8v*)(reg1 + ea * 128 + (((step * 4 + lkg) ^ (ea & 7)) * 16));
#pragma unroll
        for (int nt = 0; nt < 4; ++nt) {
          const int o = nt * 16 + lrow;
          const short8v B = *(const short8v*)(reg2 + o * 128 + (((step * 4 + lkg) ^ (o & 7)) * 16));
          accB[mt][nt] = __builtin_amdgcn_mfma_f32_16x16x32_bf16(A, B, accB[mt][nt], 0, 0, 0);
        }
      }
    }
    __syncthreads();

#pragma unroll
    for (int mt = 0; mt < 2; ++mt) {
#pragma unroll
      for (int r = 0; r < 4; ++r) {
        const int eo = wv * 32 + mt * 16 + lkg * 4 + r;
#pragma unroll
        for (int nt = 0; nt < 4; ++nt) {
          const int o = nt * 16 + lrow;
          const float val = silu(accB[mt][nt][r] * 0.125f);
          *(unsigned short*)(reg1 + eo * 128 + (((o >> 3) ^ (eo & 7)) * 16) + (o & 7) * 2) = f2bf(val);
        }
      }
    }
  }
  for (int x = t; x < 8192; x += 256) {
    const int k = x >> 7, c = x & 127;
    *(unsigned short*)(reg2 + c * 128 + (((k >> 3) ^ (c & 7)) * 16) + (k & 7) * 2) = f2bf(fw3[x]);
  }
  __syncthreads();

  {
    f32x4 accd[2][8];
#pragma unroll
    for (int mt = 0; mt < 2; ++mt)
#pragma unroll
      for (int nt = 0; nt < 8; ++nt)
        accd[mt][nt] = (f32x4){0.f, 0.f, 0.f, 0.f};

#pragma unroll
    for (int step = 0; step < 2; ++step) {
      const int ea0 = wv * 32 + lrow;
      const int ea1 = wv * 32 + 16 + lrow;
      const short8v A0 = *(const short8v*)(reg1 + ea0 * 128 + (((step * 4 + lkg) ^ (ea0 & 7)) * 16));
      const short8v A1 = *(const short8v*)(reg1 + ea1 * 128 + (((step * 4 + lkg) ^ (ea1 & 7)) * 16));
#pragma unroll
      for (int nt = 0; nt < 8; ++nt) {
        const int n = nt * 16 + lrow;
        const short8v B = *(const short8v*)(reg2 + n * 128 + (((step * 4 + lkg) ^ (n & 7)) * 16));
        accd[0][nt] = __builtin_amdgcn_mfma_f32_16x16x32_bf16(A0, B, accd[0][nt], 0, 0, 0);
        accd[1][nt] = __builtin_amdgcn_mfma_f32_16x16x32_bf16(A1, B, accd[1][nt], 0, 0, 0);
      }
    }
#pragma unroll
    for (int mt = 0; mt < 2; ++mt) {
#pragma unroll
      for (int r = 0; r < 4; ++r) {
        const int eo = wv * 32 + mt * 16 + lkg * 4 + r;
        const int slot = base + eo;
        if (slot < E) {
          unsigned short* wrow = wbuf + (size_t)slot * 128;
#pragma unroll
          for (int nt = 0; nt < 8; ++nt) {
            const int uu = (nt & 1) * 16 + lrow;
            const int comp = nt >> 1;
            wrow[uu * 4 + comp] = f2bf(accd[mt][nt][r] * 0.125f);
          }
        }
      }
    }
  }
}

// ---------------- Kernel 3: wave-per-node gather, bf16 y + w, chunked ------
__global__ __launch_bounds__(256) void gather_out_kernel(
    const float* __restrict__ nf, const unsigned short* __restrict__ wbuf,
    const unsigned short* __restrict__ yb, const float* __restrict__ sc,
    const float* __restrict__ l2w0, const float* __restrict__ l2w1,
    const int* __restrict__ offsets, const int* __restrict__ srcS,
    const float4* __restrict__ eaS,
    const int* __restrict__ avgp, float* __restrict__ out, int N, int E)
{
  __shared__ float mW[4][264];    // per-wave m[256] (+pad)
  __shared__ float soW[4][160];   // per-wave so0[64] + so1[96]
  const int t = threadIdx.x;
  const int wv = t >> 6, l = t & 63;
  const int n = blockIdx.x * 4 + wv;
  const bool valid = (n < N);
  const int u = l & 31, half = l >> 5;

  const int beg = valid ? offsets[n] : 0;
  const int end = valid ? offsets[n + 1] : 0;
  const int s0 = beg + half;
  const int cnt = (s0 < end) ? ((end - s0 + 1) >> 1) : 0;

  float a_s0 = 0.f, a_s1 = 0.f;
  float v0x = 0.f, v0y = 0.f, v0z = 0.f;
  float v1x = 0.f, v1y = 0.f, v1z = 0.f;

  int i = 0;
  for (; i + 4 <= cnt; i += 4) {
    int csrc[4]; float4 cea[4]; uint2 cw[4];
#pragma unroll
    for (int q = 0; q < 4; ++q) {
      const int sq = s0 + 2 * (i + q);
      csrc[q] = srcS[sq];
      cea[q]  = eaS[sq];
      cw[q]   = *(const uint2*)(wbuf + (size_t)sq * 128 + u * 4);
    }
    uint2 cg[4];
#pragma unroll
    for (int q = 0; q < 4; ++q)
      cg[q] = *(const uint2*)(yb + (size_t)csrc[q] * 128 + u * 4);
#pragma unroll
    for (int q = 0; q < 4; ++q) {
      const float w00 = __uint_as_float(cw[q].x << 16);
      const float w01 = __uint_as_float(cw[q].x & 0xffff0000u);
      const float w10 = __uint_as_float(cw[q].y << 16);
      const float w11 = __uint_as_float(cw[q].y & 0xffff0000u);
      const float g0  = __uint_as_float(cg[q].x << 16);
      const float g1x = __uint_as_float(cg[q].x & 0xffff0000u);
      const float g1y = __uint_as_float(cg[q].y << 16);
      const float g1z = __uint_as_float(cg[q].y & 0xffff0000u);
      a_s0 += w00 * g0 * cea[q].x;
      const float t01 = w01 * g0;
      v0x += t01 * cea[q].y; v0y += t01 * cea[q].z; v0z += t01 * cea[q].w;
      const float wg = w10 * cea[q].x;
      v1x += wg * g1x; v1y += wg * g1y; v1z += wg * g1z;
      a_s1 += w11 * (g1x * cea[q].y + g1y * cea[q].z + g1z * cea[q].w);
    }
  }
  for (; i < cnt; ++i) {
    const int sq = s0 + 2 * i;
    const int src = srcS[sq];
    const float4 ea = eaS[sq];
    const uint2 wr = *(const uint2*)(wbuf + (size_t)sq * 128 + u * 4);
    const uint2 g2 = *(const uint2*)(yb + (size_t)src * 128 + u * 4);
    const float w00 = __uint_as_float(wr.x << 16);
    const float w01 = __uint_as_float(wr.x & 0xffff0000u);
    const float w10 = __uint_as_float(wr.y << 16);
    const float w11 = __uint_as_float(wr.y & 0xffff0000u);
    const float g0  = __uint_as_float(g2.x << 16);
    const float g1x = __uint_as_float(g2.x & 0xffff0000u);
    const float g1y = __uint_as_float(g2.y << 16);
    const float g1z = __uint_as_float(g2.y & 0xffff0000u);
    a_s0 += w00 * g0 * ea.x;
    const float t01 = w01 * g0;
    v0x += t01 * ea.y; v0y += t01 * ea.z; v0z += t01 * ea.w;
    const float wg = w10 * ea.x;
    v1x += wg * g1x; v1y += wg * g1y; v1z += wg * g1z;
    a_s1 += w11 * (g1x * ea.y + g1y * ea.z + g1z * ea.w);
  }

  a_s0 += __shfl_xor(a_s0, 32);  a_s1 += __shfl_xor(a_s1, 32);
  v0x += __shfl_xor(v0x, 32); v0y += __shfl_xor(v0y, 32); v0z += __shfl_xor(v0z, 32);
  v1x += __shfl_xor(v1x, 32); v1y += __shfl_xor(v1y, 32); v1z += __shfl_xor(v1z, 32);
  if (half == 0) {
    mW[wv][u]          = a_s0;
    mW[wv][32 + u]     = a_s1 * 0.5773502691896258f;
    mW[wv][64 + 3 * u] = v0x; mW[wv][65 + 3 * u] = v0y; mW[wv][66 + 3 * u] = v0z;
    mW[wv][160 + 3 * u] = v1x; mW[wv][161 + 3 * u] = v1y; mW[wv][162 + 3 * u] = v1z;
  }
  __syncthreads();

  const float scl = 0.125f * rsqrtf((float)(*avgp));
  const float* m = mW[wv];
  if (valid) {
    {
      float acc = 0.f;
      for (int uu = 0; uu < 64; ++uu) acc += m[uu] * l2w0[uu * 64 + l];
      soW[wv][l] = acc * scl + sc[(size_t)n * 160 + l];
    }
    {
      const int w = l / 3, i2 = l - 3 * w;
      float acc = 0.f;
      for (int uu = 0; uu < 64; ++uu) acc += m[64 + uu * 3 + i2] * l2w1[uu * 32 + w];
      soW[wv][64 + l] = acc * scl + sc[(size_t)n * 160 + 64 + l];
    }
    if (l < 32) {
      const int q = 64 + l, w = q / 3, i2 = q - 3 * w;
      float acc = 0.f;
      for (int uu = 0; uu < 64; ++uu) acc += m[64 + uu * 3 + i2] * l2w1[uu * 32 + w];
      soW[wv][64 + q] = acc * scl + sc[(size_t)n * 160 + 64 + q];
    }
  }
  __syncthreads();

  if (valid) {
#pragma unroll
    for (int p = 0; p < 2; ++p) {
      const int c = p * 64 + l;
      float val;
      if (c < 32) {
        val = silu(soW[wv][c]);
      } else {
        const int q = c - 32, w = q / 3, i2 = q - 3 * w;
        val = silu(soW[wv][32 + w]) * soW[wv][64 + w * 3 + i2];
      }
      out[(size_t)n * 128 + c] = nf[(size_t)n * 128 + c] + val;
    }
  }
}

extern "C" void kernel_launch(void* const* d_in, const int* in_sizes, int n_in,
                              void* d_out, int out_size, void* d_ws, size_t ws_size,
                              hipStream_t stream)
{
  const float* nf    = (const float*)d_in[0];
  const float* na    = (const float*)d_in[1];
  const float* eattr = (const float*)d_in[2];
  const float* eemb  = (const float*)d_in[3];
  const float* l1w0  = (const float*)d_in[4];
  const float* l1w1  = (const float*)d_in[5];
  const float* fw1   = (const float*)d_in[6];
  const float* fw2   = (const float*)d_in[7];
  const float* fw3   = (const float*)d_in[8];
  const float* l2w0  = (const float*)d_in[9];
  const float* l2w1  = (const float*)d_in[10];
  const float* scw0  = (const float*)d_in[11];
  const float* scw1  = (const float*)d_in[12];
  const int*   eidx  = (const int*)d_in[13];
  const int*   avgp  = (const int*)d_in[14];

  const int N = in_sizes[0] / 128;
  const int E = in_sizes[2] / 4;

  float* yf      = (float*)d_ws;                    // N*128 floats reserved; used as bf16
  unsigned short* yb = (unsigned short*)yf;         // N*128 bf16 (interleaved g)
  float* sc      = yf + (size_t)N * 128;            // N*160
  float* wbuff   = sc + (size_t)N * 160;            // E*128 floats reserved
  unsigned short* wbuf = (unsigned short*)wbuff;    // E*128 bf16 (= E*64 floats)
  int*    srcS   = (int*)(wbuff + (size_t)E * 64);  // E ints
  float4* eaS    = (float4*)(wbuff + (size_t)E * 64 + E);  // E float4
  int*   counts  = (int*)(wbuff + (size_t)E * 128); // N
  int*   offsets = counts + N;                      // N+1
  int*   cursor  = offsets + N + 1;                 // N
  int*   elist   = cursor + N;                      // E

  hipMemsetAsync(counts, 0, (size_t)N * sizeof(int), stream);
  node_pre_kernel<<<(N + 31) / 32, 256, 0, stream>>>(nf, na, l1w0, l1w1, scw0, scw1, yb, sc, N);
  hist_kernel<<<(E + 255) / 256, 256, 0, stream>>>(eidx, counts, E);
  scan_kernel<<<1, 1024, 0, stream>>>(counts, offsets, cursor, N);
  scatter_kernel<<<(E + 255) / 256, 256, 0, stream>>>(eidx, eattr, cursor, elist, srcS, eaS, E);
  edge_mlp_kernel<<<(E + 127) / 128, 256, 0, stream>>>(eemb, fw1, fw2, fw3, elist, wbuf, E);
  gather_out_kernel<<<(N + 3) / 4, 256, 0, stream>>>(nf, wbuf, yb, sc, l2w0, l2w1,
                                                     offsets, srcS, eaS, avgp,
                                                     (float*)d_out, N, E);
}